// Round 2
// baseline (143.299 us; speedup 1.0000x reference)
//
#include <hip/hip_runtime.h>
#include <hip/hip_bf16.h>
#include <math.h>

#define BB 256
#define NN 2048
#define MM 64
#define INF_ 128
#define HH 100
#define EPSF 1e-8f
#define PSTRIDE 272

struct Ptrs { const float* p[32]; };

__device__ __forceinline__ float softplusf(float x) {
    return fmaxf(x, 0.0f) + log1pf(__expf(-fabsf(x)));
}
__device__ __forceinline__ float sigmoidf(float x) {
    return 1.0f / (1.0f + __expf(-x));
}

// ---------------------------------------------------------------------------
// Kernel 1: controller h = x@Wc + bc, then all head parameters per batch row.
// Params layout per b (stride PSTRIDE floats):
//  [0..63] k_w   [64..127] k_r   [128..191] e   [192..255] a
//  [256] coef_w = softplus(beta_w)/max(||k_w||,EPS)   [257] coef_r
//  [258] gamma_w  [259] gamma_r  [260] g_w  [261] g_r
//  [262..264] s_w  [265..267] s_r
// ---------------------------------------------------------------------------
__global__ void __launch_bounds__(128) k_params(Ptrs in, float* __restrict__ params)
{
    __shared__ float xs[INF_];
    __shared__ float hs[HH];
    __shared__ float kw[MM], kr[MM];
    __shared__ float sc[2];

    const int b = blockIdx.x, tid = threadIdx.x;
    const float* x  = in.p[0];
    const float* Wc = in.p[1];
    const float* bc = in.p[2];

    xs[tid] = x[b * INF_ + tid];
    __syncthreads();

    if (tid < HH) {
        float acc = bc[tid];
        #pragma unroll 4
        for (int i = 0; i < INF_; ++i)
            acc = fmaf(xs[i], Wc[i * HH + tid], acc);
        hs[tid] = acc;
    }
    __syncthreads();

    float* P = params + (size_t)b * PSTRIDE;

    for (int t = tid; t < 268; t += 128) {
        float acc;
        if (t < 64) {                       // k_w
            const float* W = in.p[23]; const float* bi = in.p[24];
            acc = bi[t];
            for (int j = 0; j < HH; ++j) acc = fmaf(hs[j], W[j * 64 + t], acc);
            kw[t] = acc; P[t] = acc;
        } else if (t < 128) {               // k_r
            int m = t - 64;
            const float* W = in.p[13]; const float* bi = in.p[14];
            acc = bi[m];
            for (int j = 0; j < HH; ++j) acc = fmaf(hs[j], W[j * 64 + m], acc);
            kr[m] = acc; P[64 + m] = acc;
        } else if (t < 192) {               // e
            int m = t - 128;
            const float* W = in.p[25]; const float* bi = in.p[26];
            acc = bi[m];
            for (int j = 0; j < HH; ++j) acc = fmaf(hs[j], W[j * 64 + m], acc);
            P[128 + m] = sigmoidf(acc);
        } else if (t < 256) {               // a
            int m = t - 192;
            const float* W = in.p[27]; const float* bi = in.p[28];
            acc = bi[m];
            for (int j = 0; j < HH; ++j) acc = fmaf(hs[j], W[j * 64 + m], acc);
            P[192 + m] = acc;
        } else if (t < 259) {               // s_w
            int c = t - 256;
            const float* W = in.p[21]; const float* bi = in.p[22];
            acc = bi[c];
            for (int j = 0; j < HH; ++j) acc = fmaf(hs[j], W[j * 3 + c], acc);
            P[262 + c] = acc;
        } else if (t < 262) {               // s_r
            int c = t - 259;
            const float* W = in.p[11]; const float* bi = in.p[12];
            acc = bi[c];
            for (int j = 0; j < HH; ++j) acc = fmaf(hs[j], W[j * 3 + c], acc);
            P[265 + c] = acc;
        } else if (t == 262) {              // beta_w
            const float* W = in.p[15]; const float* bi = in.p[16];
            acc = bi[0];
            for (int j = 0; j < HH; ++j) acc = fmaf(hs[j], W[j], acc);
            sc[0] = softplusf(acc);
        } else if (t == 263) {              // gamma_w
            const float* W = in.p[17]; const float* bi = in.p[18];
            acc = bi[0];
            for (int j = 0; j < HH; ++j) acc = fmaf(hs[j], W[j], acc);
            P[258] = 1.0f + softplusf(acc);
        } else if (t == 264) {              // g_w
            const float* W = in.p[19]; const float* bi = in.p[20];
            acc = bi[0];
            for (int j = 0; j < HH; ++j) acc = fmaf(hs[j], W[j], acc);
            P[260] = sigmoidf(acc);
        } else if (t == 265) {              // beta_r
            const float* W = in.p[5]; const float* bi = in.p[6];
            acc = bi[0];
            for (int j = 0; j < HH; ++j) acc = fmaf(hs[j], W[j], acc);
            sc[1] = softplusf(acc);
        } else if (t == 266) {              // gamma_r
            const float* W = in.p[7]; const float* bi = in.p[8];
            acc = bi[0];
            for (int j = 0; j < HH; ++j) acc = fmaf(hs[j], W[j], acc);
            P[259] = 1.0f + softplusf(acc);
        } else {                            // g_r
            const float* W = in.p[9]; const float* bi = in.p[10];
            acc = bi[0];
            for (int j = 0; j < HH; ++j) acc = fmaf(hs[j], W[j], acc);
            P[261] = sigmoidf(acc);
        }
    }
    __syncthreads();
    if (tid == 0) {
        float s = 0.f;
        for (int m = 0; m < MM; ++m) s = fmaf(kw[m], kw[m], s);
        P[256] = sc[0] / fmaxf(sqrtf(s), EPSF);
    }
    if (tid == 1) {
        float s = 0.f;
        for (int m = 0; m < MM; ++m) s = fmaf(kr[m], kr[m], s);
        P[257] = sc[1] / fmaxf(sqrtf(s), EPSF);
    }
}

// ---------------------------------------------------------------------------
// Kernel 2: per-(b,n) scaled-cosine logits. PASS=0: against memory_bias.
// PASS=1: against reconstructed mem = mb*(1-w*e) + w*a.
// 8-lane groups; each lane owns 8 contiguous m's (two float4 loads).
// ---------------------------------------------------------------------------
template<int PASS>
__global__ void __launch_bounds__(256) k_logits(const float* __restrict__ mb,
                                                const float* __restrict__ params,
                                                const float* __restrict__ wa,
                                                float* __restrict__ logits)
{
    const int b = blockIdx.x >> 3, chunk = blockIdx.x & 7;
    const int tid = threadIdx.x;
    const int grp = tid >> 3, l8 = tid & 7;
    const float* P = params + (size_t)b * PSTRIDE;

    float kreg[8], ereg[8], areg[8];
    const int koff = (PASS == 0) ? 0 : 64;
    #pragma unroll
    for (int j = 0; j < 8; ++j) kreg[j] = P[koff + l8 * 8 + j];
    if (PASS == 1) {
        #pragma unroll
        for (int j = 0; j < 8; ++j) { ereg[j] = P[128 + l8 * 8 + j]; areg[j] = P[192 + l8 * 8 + j]; }
    }
    const float coef = P[256 + PASS];

    #pragma unroll
    for (int it = 0; it < 8; ++it) {
        const int n = chunk * 256 + it * 32 + grp;
        const size_t roff = (size_t)b * NN + n;
        const float4* row = reinterpret_cast<const float4*>(mb + roff * MM);
        float4 v0 = row[2 * l8], v1 = row[2 * l8 + 1];
        float f[8] = {v0.x, v0.y, v0.z, v0.w, v1.x, v1.y, v1.z, v1.w};
        float w = 0.f;
        if (PASS == 1) w = wa[roff];
        float dot = 0.f, ss = 0.f;
        #pragma unroll
        for (int j = 0; j < 8; ++j) {
            float mv = (PASS == 0) ? f[j]
                     : fmaf(f[j], fmaf(-w, ereg[j], 1.0f), w * areg[j]);
            dot = fmaf(kreg[j], mv, dot);
            ss  = fmaf(mv, mv, ss);
        }
        #pragma unroll
        for (int mask = 1; mask < 8; mask <<= 1) {
            dot += __shfl_xor(dot, mask);
            ss  += __shfl_xor(ss, mask);
        }
        if (l8 == 0) logits[roff] = coef * dot / fmaxf(sqrtf(ss), EPSF);
    }
}

// ---------------------------------------------------------------------------
// Block reduction over 256 threads (4 waves), two values at once.
// ---------------------------------------------------------------------------
__device__ __forceinline__ void bred2(float& a, float& b, bool ismax, float* red)
{
    #pragma unroll
    for (int m = 32; m; m >>= 1) {
        float ta = __shfl_xor(a, m), tb = __shfl_xor(b, m);
        if (ismax) { a = fmaxf(a, ta); b = fmaxf(b, tb); }
        else       { a += ta; b += tb; }
    }
    const int wid = threadIdx.x >> 6;
    if ((threadIdx.x & 63) == 0) { red[wid] = a; red[4 + wid] = b; }
    __syncthreads();
    float ra = red[0], rb = red[4];
    for (int w = 1; w < 4; ++w) {
        if (ismax) { ra = fmaxf(ra, red[w]); rb = fmaxf(rb, red[4 + w]); }
        else       { ra += red[w]; rb += red[4 + w]; }
    }
    __syncthreads();
    a = ra; b = rb;
}

// ---------------------------------------------------------------------------
// Kernel 3: softmax(logits), softmax(bias), interpolate, circular 3-tap conv,
// sharpen (pow gamma), normalize. In-place on the logits buffer.
// ---------------------------------------------------------------------------
__global__ void __launch_bounds__(256) k_combine(float* __restrict__ buf,
                                                 const float* __restrict__ bias,
                                                 const float* __restrict__ params,
                                                 int head)
{
    __shared__ float wcs[NN];
    __shared__ float ats[NN];
    __shared__ float red[8];

    const int b = blockIdx.x, tid = threadIdx.x;
    const float* P = params + (size_t)b * PSTRIDE;
    const float g = P[260 + head], gamma = P[258 + head];
    const float s0 = P[262 + head * 3], s1 = P[263 + head * 3], s2 = P[264 + head * 3];

    float mL = -1e30f, mB = -1e30f;
    #pragma unroll
    for (int k = 0; k < 8; ++k) {
        int i = tid + k * 256;
        float lg = buf[(size_t)b * NN + i]; wcs[i] = lg; mL = fmaxf(mL, lg);
        float bb = bias[(size_t)b * NN + i]; ats[i] = bb; mB = fmaxf(mB, bb);
    }
    __syncthreads();
    bred2(mL, mB, true, red);

    float sL = 0.f, sB = 0.f;
    #pragma unroll
    for (int k = 0; k < 8; ++k) {
        int i = tid + k * 256;
        float ew = __expf(wcs[i] - mL);
        float eb = __expf(ats[i] - mB);
        wcs[i] = ew; ats[i] = eb;
        sL += ew; sB += eb;
    }
    bred2(sL, sB, false, red);
    const float iL = 1.0f / sL, iB = 1.0f / sB;

    #pragma unroll
    for (int k = 0; k < 8; ++k) {
        int i = tid + k * 256;
        float wg = g * wcs[i] * iL + (1.0f - g) * ats[i] * iB;
        ats[i] = wg;
    }
    __syncthreads();

    float pv[8]; float ps = 0.f;
    #pragma unroll
    for (int k = 0; k < 8; ++k) {
        int i = tid + k * 256;
        float tw = s0 * ats[(i + NN - 1) & (NN - 1)]
                 + s1 * ats[i]
                 + s2 * ats[(i + 1) & (NN - 1)];
        float p = powf(tw, gamma);
        pv[k] = p; ps += p;
    }
    float dummy = 0.f;
    bred2(ps, dummy, false, red);
    const float inv = 1.0f / (EPSF + ps);
    #pragma unroll
    for (int k = 0; k < 8; ++k) {
        int i = tid + k * 256;
        buf[(size_t)b * NN + i] = pv[k] * inv;
    }
}

// ---------------------------------------------------------------------------
// Kernel 4a: partial r = sum_n r_attn * mem over a 256-row chunk.
// Grid BB*8; partial sums [B,8,64] into workspace.
// ---------------------------------------------------------------------------
__global__ void __launch_bounds__(256) k_read_partial(const float* __restrict__ mb,
                                                      const float* __restrict__ params,
                                                      const float* __restrict__ wattn,
                                                      const float* __restrict__ rattn,
                                                      float* __restrict__ rpart)
{
    __shared__ float acc_s[32 * 64];

    const int b = blockIdx.x >> 3, chunk = blockIdx.x & 7;
    const int tid = threadIdx.x;
    const int grp = tid >> 3, l8 = tid & 7;
    const float* P = params + (size_t)b * PSTRIDE;

    float ereg[8], areg[8];
    #pragma unroll
    for (int j = 0; j < 8; ++j) { ereg[j] = P[128 + l8 * 8 + j]; areg[j] = P[192 + l8 * 8 + j]; }

    float acc[8];
    #pragma unroll
    for (int j = 0; j < 8; ++j) acc[j] = 0.f;

    #pragma unroll
    for (int it = 0; it < 8; ++it) {
        const int n = chunk * 256 + it * 32 + grp;
        const size_t roff = (size_t)b * NN + n;
        const float w = wattn[roff];
        const float ra = rattn[roff];
        const float4* row = reinterpret_cast<const float4*>(mb + roff * MM);
        float4 v0 = row[2 * l8], v1 = row[2 * l8 + 1];
        float f[8] = {v0.x, v0.y, v0.z, v0.w, v1.x, v1.y, v1.z, v1.w};
        #pragma unroll
        for (int j = 0; j < 8; ++j) {
            float mv = fmaf(f[j], fmaf(-w, ereg[j], 1.0f), w * areg[j]);
            acc[j] = fmaf(ra, mv, acc[j]);
        }
    }
    #pragma unroll
    for (int j = 0; j < 8; ++j) acc_s[grp * 64 + l8 * 8 + j] = acc[j];
    __syncthreads();

    if (tid < 64) {
        float s = 0.f;
        #pragma unroll 8
        for (int g2 = 0; g2 < 32; ++g2) s += acc_s[g2 * 64 + tid];
        rpart[((size_t)b * 8 + chunk) * 64 + tid] = s;
    }
}

// ---------------------------------------------------------------------------
// Kernel 4b: r = sum of 8 partials, out = sigmoid(r@Wo + bo). fp32 out.
// ---------------------------------------------------------------------------
__global__ void __launch_bounds__(64) k_out(const float* __restrict__ rpart,
                                            const float* __restrict__ Wo,
                                            const float* __restrict__ bo,
                                            float* __restrict__ out)
{
    __shared__ float rv[64];
    const int b = blockIdx.x, tid = threadIdx.x;

    float s = 0.f;
    #pragma unroll
    for (int k = 0; k < 8; ++k) s += rpart[((size_t)b * 8 + k) * 64 + tid];
    rv[tid] = s;
    __syncthreads();

    float o = bo[tid];
    #pragma unroll 4
    for (int m = 0; m < 64; ++m) o = fmaf(rv[m], Wo[m * 64 + tid], o);
    out[(size_t)b * 64 + tid] = sigmoidf(o);
}

// ---------------------------------------------------------------------------
extern "C" void kernel_launch(void* const* d_in, const int* in_sizes, int n_in,
                              void* d_out, int out_size, void* d_ws, size_t ws_size,
                              hipStream_t stream)
{
    Ptrs in;
    for (int i = 0; i < 32; ++i) in.p[i] = (const float*)d_in[i];

    float* params = (float*)d_ws;                        // 256*272 floats
    float* bufW = params + (size_t)BB * PSTRIDE;         // B*N: logits_w -> w_attn
    float* bufR = bufW + (size_t)BB * NN;                // B*N: logits_r -> r_attn
    float* rpart = bufR + (size_t)BB * NN;               // B*8*64

    const float* mb     = (const float*)d_in[31];
    const float* r_bias = (const float*)d_in[29];
    const float* w_bias = (const float*)d_in[30];

    k_params<<<BB, 128, 0, stream>>>(in, params);
    k_logits<0><<<BB * 8, 256, 0, stream>>>(mb, params, bufW, bufW);
    k_combine<<<BB, 256, 0, stream>>>(bufW, w_bias, params, 0);
    k_logits<1><<<BB * 8, 256, 0, stream>>>(mb, params, bufW, bufR);
    k_combine<<<BB, 256, 0, stream>>>(bufR, r_bias, params, 1);
    k_read_partial<<<BB * 8, 256, 0, stream>>>(mb, params, bufW, bufR, rpart);
    k_out<<<BB, 64, 0, stream>>>(rpart, (const float*)d_in[3], (const float*)d_in[4],
                                 (float*)d_out);
}

// Round 3
// 101.494 us; speedup vs baseline: 1.4119x; 1.4119x over previous
//
#include <hip/hip_runtime.h>
#include <hip/hip_bf16.h>
#include <math.h>

#define BB 256
#define NN 2048
#define MM 64
#define INF_ 128
#define HH 100
#define EPSF 1e-8f
#define PSTRIDE 272

struct Ptrs { const float* p[32]; };

__device__ __forceinline__ float softplusf(float x) {
    return fmaxf(x, 0.0f) + log1pf(__expf(-fabsf(x)));
}
__device__ __forceinline__ float sigmoidf(float x) {
    return 1.0f / (1.0f + __expf(-x));
}

// ---------------------------------------------------------------------------
// Kernel 1: controller h = x@Wc + bc, then all head parameters per batch row.
// Wave-uniform structure: no divergent 100-iter loops.
// Params layout per b (stride PSTRIDE floats):
//  [0..63] k_w   [64..127] k_r   [128..191] e   [192..255] a
//  [256] coef_w = softplus(beta_w)/max(||k_w||,EPS)   [257] coef_r
//  [258] gamma_w  [259] gamma_r  [260] g_w  [261] g_r
//  [262..264] s_w  [265..267] s_r
// ---------------------------------------------------------------------------
__global__ void __launch_bounds__(256) k_params(Ptrs in, float* __restrict__ params)
{
    __shared__ float xs[INF_];
    __shared__ float hs[HH];
    __shared__ float kws[MM], krs[MM];
    __shared__ float sc[2];

    const int b = blockIdx.x, tid = threadIdx.x;
    const int lane = tid & 63, wv = tid >> 6;

    if (tid < INF_) xs[tid] = in.p[0][b * INF_ + tid];
    __syncthreads();

    // ---- h = x @ Wc + bc (100 outputs, 1 thread each, 8 loads in flight)
    if (tid < HH) {
        const float* Wc = in.p[1];
        float acc = in.p[2][tid];
        #pragma unroll 8
        for (int i = 0; i < INF_; ++i)
            acc = fmaf(xs[i], Wc[i * HH + tid], acc);
        hs[tid] = acc;
    }
    __syncthreads();

    float* P = params + (size_t)b * PSTRIDE;

    // ---- four 64-wide heads: wave 0 -> k_w, 1 -> k_r, 2 -> e, 3 -> a
    {
        const int m = lane;
        const float* W; const float* bi;
        if      (wv == 0) { W = in.p[23]; bi = in.p[24]; }
        else if (wv == 1) { W = in.p[13]; bi = in.p[14]; }
        else if (wv == 2) { W = in.p[25]; bi = in.p[26]; }
        else              { W = in.p[27]; bi = in.p[28]; }
        float acc = bi[m];
        #pragma unroll 10
        for (int j = 0; j < HH; ++j)
            acc = fmaf(hs[j], W[j * 64 + m], acc);
        if      (wv == 0) { kws[m] = acc; P[m] = acc; }
        else if (wv == 1) { krs[m] = acc; P[64 + m] = acc; }
        else if (wv == 2) { P[128 + m] = sigmoidf(acc); }
        else              { P[192 + m] = acc; }
    }

    // ---- 12 scalar heads: 3 per wave, full-wave shuffle reduce each
    {
        const float* Wt[3]; int strd;
        if      (wv == 0) { Wt[0] = in.p[15]; Wt[1] = in.p[17]; Wt[2] = in.p[19]; strd = 1; }
        else if (wv == 1) { Wt[0] = in.p[5];  Wt[1] = in.p[7];  Wt[2] = in.p[9];  strd = 1; }
        else if (wv == 2) { Wt[0] = in.p[21]; Wt[1] = in.p[21]; Wt[2] = in.p[21]; strd = 3; }
        else              { Wt[0] = in.p[11]; Wt[1] = in.p[11]; Wt[2] = in.p[11]; strd = 3; }

        #pragma unroll
        for (int sidx = 0; sidx < 3; ++sidx) {
            const float* W = Wt[sidx];
            const int off = (strd == 3) ? sidx : 0;
            float v = 0.f;
            if (lane < HH)      v = hs[lane] * W[lane * strd + off];
            if (lane < HH - 64) v = fmaf(hs[lane + 64], W[(lane + 64) * strd + off], v);
            #pragma unroll
            for (int m2 = 32; m2; m2 >>= 1) v += __shfl_xor(v, m2);
            if (lane == 0) {
                if (wv == 0) {
                    if      (sidx == 0) sc[0]  = softplusf(v + in.p[16][0]);
                    else if (sidx == 1) P[258] = 1.0f + softplusf(v + in.p[18][0]);
                    else                P[260] = sigmoidf(v + in.p[20][0]);
                } else if (wv == 1) {
                    if      (sidx == 0) sc[1]  = softplusf(v + in.p[6][0]);
                    else if (sidx == 1) P[259] = 1.0f + softplusf(v + in.p[8][0]);
                    else                P[261] = sigmoidf(v + in.p[10][0]);
                } else if (wv == 2) {
                    P[262 + sidx] = v + in.p[22][sidx];
                } else {
                    P[265 + sidx] = v + in.p[12][sidx];
                }
            }
        }
    }
    __syncthreads();

    // ---- coef = softplus(beta) / max(||k||, EPS), wave-parallel
    if (wv == 0) {
        float v = kws[lane] * kws[lane];
        #pragma unroll
        for (int m2 = 32; m2; m2 >>= 1) v += __shfl_xor(v, m2);
        if (lane == 0) P[256] = sc[0] / fmaxf(sqrtf(v), EPSF);
    }
    if (wv == 1) {
        float v = krs[lane] * krs[lane];
        #pragma unroll
        for (int m2 = 32; m2; m2 >>= 1) v += __shfl_xor(v, m2);
        if (lane == 0) P[257] = sc[1] / fmaxf(sqrtf(v), EPSF);
    }
}

// ---------------------------------------------------------------------------
// Kernel 2: per-(b,n) scaled-cosine logits. PASS=0: against memory_bias.
// PASS=1: against reconstructed mem = mb*(1-w*e) + w*a.
// 8-lane groups; each lane owns 8 contiguous m's (two float4 loads).
// ---------------------------------------------------------------------------
template<int PASS>
__global__ void __launch_bounds__(256) k_logits(const float* __restrict__ mb,
                                                const float* __restrict__ params,
                                                const float* __restrict__ wa,
                                                float* __restrict__ logits)
{
    const int b = blockIdx.x >> 3, chunk = blockIdx.x & 7;
    const int tid = threadIdx.x;
    const int grp = tid >> 3, l8 = tid & 7;
    const float* P = params + (size_t)b * PSTRIDE;

    float kreg[8], ereg[8], areg[8];
    const int koff = (PASS == 0) ? 0 : 64;
    #pragma unroll
    for (int j = 0; j < 8; ++j) kreg[j] = P[koff + l8 * 8 + j];
    if (PASS == 1) {
        #pragma unroll
        for (int j = 0; j < 8; ++j) { ereg[j] = P[128 + l8 * 8 + j]; areg[j] = P[192 + l8 * 8 + j]; }
    }
    const float coef = P[256 + PASS];

    #pragma unroll
    for (int it = 0; it < 8; ++it) {
        const int n = chunk * 256 + it * 32 + grp;
        const size_t roff = (size_t)b * NN + n;
        const float4* row = reinterpret_cast<const float4*>(mb + roff * MM);
        float4 v0 = row[2 * l8], v1 = row[2 * l8 + 1];
        float f[8] = {v0.x, v0.y, v0.z, v0.w, v1.x, v1.y, v1.z, v1.w};
        float w = 0.f;
        if (PASS == 1) w = wa[roff];
        float dot = 0.f, ss = 0.f;
        #pragma unroll
        for (int j = 0; j < 8; ++j) {
            float mv = (PASS == 0) ? f[j]
                     : fmaf(f[j], fmaf(-w, ereg[j], 1.0f), w * areg[j]);
            dot = fmaf(kreg[j], mv, dot);
            ss  = fmaf(mv, mv, ss);
        }
        #pragma unroll
        for (int mask = 1; mask < 8; mask <<= 1) {
            dot += __shfl_xor(dot, mask);
            ss  += __shfl_xor(ss, mask);
        }
        if (l8 == 0) logits[roff] = coef * dot / fmaxf(sqrtf(ss), EPSF);
    }
}

// ---------------------------------------------------------------------------
// Block reduction over 256 threads (4 waves), two values at once.
// ---------------------------------------------------------------------------
__device__ __forceinline__ void bred2(float& a, float& b, bool ismax, float* red)
{
    #pragma unroll
    for (int m = 32; m; m >>= 1) {
        float ta = __shfl_xor(a, m), tb = __shfl_xor(b, m);
        if (ismax) { a = fmaxf(a, ta); b = fmaxf(b, tb); }
        else       { a += ta; b += tb; }
    }
    const int wid = threadIdx.x >> 6;
    if ((threadIdx.x & 63) == 0) { red[wid] = a; red[4 + wid] = b; }
    __syncthreads();
    float ra = red[0], rb = red[4];
    for (int w = 1; w < 4; ++w) {
        if (ismax) { ra = fmaxf(ra, red[w]); rb = fmaxf(rb, red[4 + w]); }
        else       { ra += red[w]; rb += red[4 + w]; }
    }
    __syncthreads();
    a = ra; b = rb;
}

// ---------------------------------------------------------------------------
// Kernel 3: softmax(logits), softmax(bias), interpolate, circular 3-tap conv,
// sharpen (pow gamma), normalize. In-place on the logits buffer.
// ---------------------------------------------------------------------------
__global__ void __launch_bounds__(256) k_combine(float* __restrict__ buf,
                                                 const float* __restrict__ bias,
                                                 const float* __restrict__ params,
                                                 int head)
{
    __shared__ float wcs[NN];
    __shared__ float ats[NN];
    __shared__ float red[8];

    const int b = blockIdx.x, tid = threadIdx.x;
    const float* P = params + (size_t)b * PSTRIDE;
    const float g = P[260 + head], gamma = P[258 + head];
    const float s0 = P[262 + head * 3], s1 = P[263 + head * 3], s2 = P[264 + head * 3];

    float mL = -1e30f, mB = -1e30f;
    #pragma unroll
    for (int k = 0; k < 8; ++k) {
        int i = tid + k * 256;
        float lg = buf[(size_t)b * NN + i]; wcs[i] = lg; mL = fmaxf(mL, lg);
        float bb = bias[(size_t)b * NN + i]; ats[i] = bb; mB = fmaxf(mB, bb);
    }
    __syncthreads();
    bred2(mL, mB, true, red);

    float sL = 0.f, sB = 0.f;
    #pragma unroll
    for (int k = 0; k < 8; ++k) {
        int i = tid + k * 256;
        float ew = __expf(wcs[i] - mL);
        float eb = __expf(ats[i] - mB);
        wcs[i] = ew; ats[i] = eb;
        sL += ew; sB += eb;
    }
    bred2(sL, sB, false, red);
    const float iL = 1.0f / sL, iB = 1.0f / sB;

    #pragma unroll
    for (int k = 0; k < 8; ++k) {
        int i = tid + k * 256;
        float wg = g * wcs[i] * iL + (1.0f - g) * ats[i] * iB;
        ats[i] = wg;
    }
    __syncthreads();

    float pv[8]; float ps = 0.f;
    #pragma unroll
    for (int k = 0; k < 8; ++k) {
        int i = tid + k * 256;
        float tw = s0 * ats[(i + NN - 1) & (NN - 1)]
                 + s1 * ats[i]
                 + s2 * ats[(i + 1) & (NN - 1)];
        float p = powf(tw, gamma);
        pv[k] = p; ps += p;
    }
    float dummy = 0.f;
    bred2(ps, dummy, false, red);
    const float inv = 1.0f / (EPSF + ps);
    #pragma unroll
    for (int k = 0; k < 8; ++k) {
        int i = tid + k * 256;
        buf[(size_t)b * NN + i] = pv[k] * inv;
    }
}

// ---------------------------------------------------------------------------
// Kernel 4a: partial r = sum_n r_attn * mem over a 256-row chunk.
// Grid BB*8; partial sums [B,8,64] into workspace.
// ---------------------------------------------------------------------------
__global__ void __launch_bounds__(256) k_read_partial(const float* __restrict__ mb,
                                                      const float* __restrict__ params,
                                                      const float* __restrict__ wattn,
                                                      const float* __restrict__ rattn,
                                                      float* __restrict__ rpart)
{
    __shared__ float acc_s[32 * 64];

    const int b = blockIdx.x >> 3, chunk = blockIdx.x & 7;
    const int tid = threadIdx.x;
    const int grp = tid >> 3, l8 = tid & 7;
    const float* P = params + (size_t)b * PSTRIDE;

    float ereg[8], areg[8];
    #pragma unroll
    for (int j = 0; j < 8; ++j) { ereg[j] = P[128 + l8 * 8 + j]; areg[j] = P[192 + l8 * 8 + j]; }

    float acc[8];
    #pragma unroll
    for (int j = 0; j < 8; ++j) acc[j] = 0.f;

    #pragma unroll
    for (int it = 0; it < 8; ++it) {
        const int n = chunk * 256 + it * 32 + grp;
        const size_t roff = (size_t)b * NN + n;
        const float w = wattn[roff];
        const float ra = rattn[roff];
        const float4* row = reinterpret_cast<const float4*>(mb + roff * MM);
        float4 v0 = row[2 * l8], v1 = row[2 * l8 + 1];
        float f[8] = {v0.x, v0.y, v0.z, v0.w, v1.x, v1.y, v1.z, v1.w};
        #pragma unroll
        for (int j = 0; j < 8; ++j) {
            float mv = fmaf(f[j], fmaf(-w, ereg[j], 1.0f), w * areg[j]);
            acc[j] = fmaf(ra, mv, acc[j]);
        }
    }
    #pragma unroll
    for (int j = 0; j < 8; ++j) acc_s[grp * 64 + l8 * 8 + j] = acc[j];
    __syncthreads();

    if (tid < 64) {
        float s = 0.f;
        #pragma unroll 8
        for (int g2 = 0; g2 < 32; ++g2) s += acc_s[g2 * 64 + tid];
        rpart[((size_t)b * 8 + chunk) * 64 + tid] = s;
    }
}

// ---------------------------------------------------------------------------
// Kernel 4b: r = sum of 8 partials, out = sigmoid(r@Wo + bo). fp32 out.
// ---------------------------------------------------------------------------
__global__ void __launch_bounds__(64) k_out(const float* __restrict__ rpart,
                                            const float* __restrict__ Wo,
                                            const float* __restrict__ bo,
                                            float* __restrict__ out)
{
    __shared__ float rv[64];
    const int b = blockIdx.x, tid = threadIdx.x;

    float s = 0.f;
    #pragma unroll
    for (int k = 0; k < 8; ++k) s += rpart[((size_t)b * 8 + k) * 64 + tid];
    rv[tid] = s;
    __syncthreads();

    float o = bo[tid];
    #pragma unroll 4
    for (int m = 0; m < 64; ++m) o = fmaf(rv[m], Wo[m * 64 + tid], o);
    out[(size_t)b * 64 + tid] = sigmoidf(o);
}

// ---------------------------------------------------------------------------
extern "C" void kernel_launch(void* const* d_in, const int* in_sizes, int n_in,
                              void* d_out, int out_size, void* d_ws, size_t ws_size,
                              hipStream_t stream)
{
    Ptrs in;
    for (int i = 0; i < 32; ++i) in.p[i] = (const float*)d_in[i];

    float* params = (float*)d_ws;                        // 256*272 floats
    float* bufW = params + (size_t)BB * PSTRIDE;         // B*N: logits_w -> w_attn
    float* bufR = bufW + (size_t)BB * NN;                // B*N: logits_r -> r_attn
    float* rpart = bufR + (size_t)BB * NN;               // B*8*64

    const float* mb     = (const float*)d_in[31];
    const float* r_bias = (const float*)d_in[29];
    const float* w_bias = (const float*)d_in[30];

    k_params<<<BB, 256, 0, stream>>>(in, params);
    k_logits<0><<<BB * 8, 256, 0, stream>>>(mb, params, bufW, bufW);
    k_combine<<<BB, 256, 0, stream>>>(bufW, w_bias, params, 0);
    k_logits<1><<<BB * 8, 256, 0, stream>>>(mb, params, bufW, bufR);
    k_combine<<<BB, 256, 0, stream>>>(bufR, r_bias, params, 1);
    k_read_partial<<<BB * 8, 256, 0, stream>>>(mb, params, bufW, bufR, rpart);
    k_out<<<BB, 64, 0, stream>>>(rpart, (const float*)d_in[3], (const float*)d_in[4],
                                 (float*)d_out);
}

// Round 4
// 85.641 us; speedup vs baseline: 1.6732x; 1.1851x over previous
//
#include <hip/hip_runtime.h>
#include <hip/hip_bf16.h>
#include <math.h>

#define BB 256
#define NN 2048
#define MM 64
#define INF_ 128
#define HH 100
#define EPSF 1e-8f
#define PSTRIDE 272

struct Ptrs { const float* p[32]; };

__device__ __forceinline__ float softplusf(float x) {
    return fmaxf(x, 0.0f) + log1pf(__expf(-fabsf(x)));
}
__device__ __forceinline__ float sigmoidf(float x) {
    return 1.0f / (1.0f + __expf(-x));
}

// ---------------------------------------------------------------------------
// Kernel 1: controller h = x@Wc + bc, then all head parameters per batch row.
// Params layout per b (stride PSTRIDE floats):
//  [0..63] k_w   [64..127] k_r   [128..191] e   [192..255] a
//  [256] coef_w = softplus(beta_w)/max(||k_w||,EPS)   [257] coef_r
//  [258] gamma_w  [259] gamma_r  [260] g_w  [261] g_r
//  [262..264] s_w  [265..267] s_r
//  [268] kra = k_r . a   [269] saa = a . a
// ---------------------------------------------------------------------------
__global__ void __launch_bounds__(256) k_params(Ptrs in, float* __restrict__ params)
{
    __shared__ float xs[INF_];
    __shared__ float hs[HH];
    __shared__ float kws[MM], krs[MM], as_[MM];
    __shared__ float sc[2];

    const int b = blockIdx.x, tid = threadIdx.x;
    const int lane = tid & 63, wv = tid >> 6;

    if (tid < INF_) xs[tid] = in.p[0][b * INF_ + tid];
    __syncthreads();

    // ---- h = x @ Wc + bc
    if (tid < HH) {
        const float* Wc = in.p[1];
        float acc = in.p[2][tid];
        #pragma unroll 8
        for (int i = 0; i < INF_; ++i)
            acc = fmaf(xs[i], Wc[i * HH + tid], acc);
        hs[tid] = acc;
    }
    __syncthreads();

    float* P = params + (size_t)b * PSTRIDE;

    // ---- four 64-wide heads: wave 0 -> k_w, 1 -> k_r, 2 -> e, 3 -> a
    {
        const int m = lane;
        const float* W; const float* bi;
        if      (wv == 0) { W = in.p[23]; bi = in.p[24]; }
        else if (wv == 1) { W = in.p[13]; bi = in.p[14]; }
        else if (wv == 2) { W = in.p[25]; bi = in.p[26]; }
        else              { W = in.p[27]; bi = in.p[28]; }
        float acc = bi[m];
        #pragma unroll 10
        for (int j = 0; j < HH; ++j)
            acc = fmaf(hs[j], W[j * 64 + m], acc);
        if      (wv == 0) { kws[m] = acc; P[m] = acc; }
        else if (wv == 1) { krs[m] = acc; P[64 + m] = acc; }
        else if (wv == 2) { P[128 + m] = sigmoidf(acc); }
        else              { as_[m] = acc; P[192 + m] = acc; }
    }

    // ---- 12 scalar heads: 3 per wave, full-wave shuffle reduce each
    {
        const float* Wt[3]; int strd;
        if      (wv == 0) { Wt[0] = in.p[15]; Wt[1] = in.p[17]; Wt[2] = in.p[19]; strd = 1; }
        else if (wv == 1) { Wt[0] = in.p[5];  Wt[1] = in.p[7];  Wt[2] = in.p[9];  strd = 1; }
        else if (wv == 2) { Wt[0] = in.p[21]; Wt[1] = in.p[21]; Wt[2] = in.p[21]; strd = 3; }
        else              { Wt[0] = in.p[11]; Wt[1] = in.p[11]; Wt[2] = in.p[11]; strd = 3; }

        #pragma unroll
        for (int sidx = 0; sidx < 3; ++sidx) {
            const float* W = Wt[sidx];
            const int off = (strd == 3) ? sidx : 0;
            float v = 0.f;
            if (lane < HH)      v = hs[lane] * W[lane * strd + off];
            if (lane < HH - 64) v = fmaf(hs[lane + 64], W[(lane + 64) * strd + off], v);
            #pragma unroll
            for (int m2 = 32; m2; m2 >>= 1) v += __shfl_xor(v, m2);
            if (lane == 0) {
                if (wv == 0) {
                    if      (sidx == 0) sc[0]  = softplusf(v + in.p[16][0]);
                    else if (sidx == 1) P[258] = 1.0f + softplusf(v + in.p[18][0]);
                    else                P[260] = sigmoidf(v + in.p[20][0]);
                } else if (wv == 1) {
                    if      (sidx == 0) sc[1]  = softplusf(v + in.p[6][0]);
                    else if (sidx == 1) P[259] = 1.0f + softplusf(v + in.p[8][0]);
                    else                P[261] = sigmoidf(v + in.p[10][0]);
                } else if (wv == 2) {
                    P[262 + sidx] = v + in.p[22][sidx];
                } else {
                    P[265 + sidx] = v + in.p[12][sidx];
                }
            }
        }
    }
    __syncthreads();

    // ---- wave-parallel reductions: coef_w, coef_r, kra, saa
    if (wv == 0) {
        float v = kws[lane] * kws[lane];
        #pragma unroll
        for (int m2 = 32; m2; m2 >>= 1) v += __shfl_xor(v, m2);
        if (lane == 0) P[256] = sc[0] / fmaxf(sqrtf(v), EPSF);
    }
    if (wv == 1) {
        float v = krs[lane] * krs[lane];
        #pragma unroll
        for (int m2 = 32; m2; m2 >>= 1) v += __shfl_xor(v, m2);
        if (lane == 0) P[257] = sc[1] / fmaxf(sqrtf(v), EPSF);
    }
    if (wv == 2) {
        float v = krs[lane] * as_[lane];
        #pragma unroll
        for (int m2 = 32; m2; m2 >>= 1) v += __shfl_xor(v, m2);
        if (lane == 0) P[268] = v;
    }
    if (wv == 3) {
        float v = as_[lane] * as_[lane];
        #pragma unroll
        for (int m2 = 32; m2; m2 >>= 1) v += __shfl_xor(v, m2);
        if (lane == 0) P[269] = v;
    }
}

// ---------------------------------------------------------------------------
// Kernel 2: SINGLE pass over memory_bias computing 8 row-summaries:
//  [0]=lw (k_w.mb)  [1]=d1 (k_r.mb)  [2]=d2 ((k_r e).mb)  [3]=s0 (mb^2)
//  [4]=s1 (mb^2 e)  [5]=s2 (mb^2 e^2) [6]=s3 (mb.a)       [7]=s4 (mb.(e a))
// AoS 8 floats per row -> both heads' logits derivable without re-reading mb.
// 8-lane groups; each lane owns 8 contiguous m's (two float4 loads).
// ---------------------------------------------------------------------------
__global__ void __launch_bounds__(256) k_summ(const float* __restrict__ mb,
                                              const float* __restrict__ params,
                                              float* __restrict__ summ)
{
    const int b = blockIdx.x >> 3, chunk = blockIdx.x & 7;
    const int tid = threadIdx.x;
    const int grp = tid >> 3, l8 = tid & 7;
    const float* P = params + (size_t)b * PSTRIDE;

    float kw[8], kr[8], kre[8], ev[8], ee[8], av[8], ea[8];
    #pragma unroll
    for (int j = 0; j < 8; ++j) {
        kw[j] = P[l8 * 8 + j];
        kr[j] = P[64 + l8 * 8 + j];
        ev[j] = P[128 + l8 * 8 + j];
        av[j] = P[192 + l8 * 8 + j];
        kre[j] = kr[j] * ev[j];
        ee[j]  = ev[j] * ev[j];
        ea[j]  = ev[j] * av[j];
    }

    #pragma unroll
    for (int it = 0; it < 8; ++it) {
        const int n = chunk * 256 + it * 32 + grp;
        const size_t roff = (size_t)b * NN + n;
        const float4* row = reinterpret_cast<const float4*>(mb + roff * MM);
        float4 v0 = row[2 * l8], v1 = row[2 * l8 + 1];
        float f[8] = {v0.x, v0.y, v0.z, v0.w, v1.x, v1.y, v1.z, v1.w};

        float acc[8];
        #pragma unroll
        for (int j = 0; j < 8; ++j) acc[j] = 0.f;
        #pragma unroll
        for (int j = 0; j < 8; ++j) {
            const float m = f[j], m2 = m * m;
            acc[0] = fmaf(kw[j],  m,  acc[0]);
            acc[1] = fmaf(kr[j],  m,  acc[1]);
            acc[2] = fmaf(kre[j], m,  acc[2]);
            acc[3] += m2;
            acc[4] = fmaf(ev[j],  m2, acc[4]);
            acc[5] = fmaf(ee[j],  m2, acc[5]);
            acc[6] = fmaf(av[j],  m,  acc[6]);
            acc[7] = fmaf(ea[j],  m,  acc[7]);
        }

        // transposing butterfly over the 8-lane group: lane l8 ends with acc[l8]
        float k1[4];
        #pragma unroll
        for (int k = 0; k < 4; ++k) {
            float snd = (l8 & 1) ? acc[2 * k] : acc[2 * k + 1];
            float rcv = __shfl_xor(snd, 1);
            k1[k] = ((l8 & 1) ? acc[2 * k + 1] : acc[2 * k]) + rcv;
        }
        float k2[2];
        #pragma unroll
        for (int k = 0; k < 2; ++k) {
            float snd = (l8 & 2) ? k1[2 * k] : k1[2 * k + 1];
            float rcv = __shfl_xor(snd, 2);
            k2[k] = ((l8 & 2) ? k1[2 * k + 1] : k1[2 * k]) + rcv;
        }
        {
            float snd = (l8 & 4) ? k2[0] : k2[1];
            float rcv = __shfl_xor(snd, 4);
            float tot = ((l8 & 4) ? k2[1] : k2[0]) + rcv;
            summ[roff * 8 + l8] = tot;
        }
    }
}

// ---------------------------------------------------------------------------
// Block reduction over 256 threads (4 waves), two values at once.
// ---------------------------------------------------------------------------
__device__ __forceinline__ void bred2(float& a, float& b, bool ismax, float* red)
{
    #pragma unroll
    for (int m = 32; m; m >>= 1) {
        float ta = __shfl_xor(a, m), tb = __shfl_xor(b, m);
        if (ismax) { a = fmaxf(a, ta); b = fmaxf(b, tb); }
        else       { a += ta; b += tb; }
    }
    const int wid = threadIdx.x >> 6;
    if ((threadIdx.x & 63) == 0) { red[wid] = a; red[4 + wid] = b; }
    __syncthreads();
    float ra = red[0], rb = red[4];
    for (int w = 1; w < 4; ++w) {
        if (ismax) { ra = fmaxf(ra, red[w]); rb = fmaxf(rb, red[4 + w]); }
        else       { ra += red[w]; rb += red[4 + w]; }
    }
    __syncthreads();
    a = ra; b = rb;
}

// ---------------------------------------------------------------------------
// Kernel 3: logits (from summaries), softmax, softmax(bias), interpolate,
// circular 3-tap conv, sharpen, normalize. HEAD=0: write, HEAD=1: read (uses
// w_attn to reconstruct mem's dot/norm algebraically).
// ---------------------------------------------------------------------------
template<int HEAD>
__global__ void __launch_bounds__(256) k_combine(const float* __restrict__ summ,
                                                 const float* __restrict__ bias,
                                                 const float* __restrict__ params,
                                                 const float* __restrict__ w_in,
                                                 float* __restrict__ out)
{
    __shared__ float wcs[NN];
    __shared__ float ats[NN];
    __shared__ float red[8];

    const int b = blockIdx.x, tid = threadIdx.x;
    const float* P = params + (size_t)b * PSTRIDE;
    const float g = P[260 + HEAD], gamma = P[258 + HEAD];
    const float s0c = P[262 + HEAD * 3], s1c = P[263 + HEAD * 3], s2c = P[264 + HEAD * 3];
    const float coef = P[256 + HEAD];
    const float kra = P[268], saa = P[269];

    float mL = -1e30f, mB = -1e30f;
    #pragma unroll
    for (int k = 0; k < 8; ++k) {
        int i = tid + k * 256;
        const size_t roff = (size_t)b * NN + i;
        const float4* s4p = reinterpret_cast<const float4*>(summ + roff * 8);
        float4 q0 = s4p[0];
        float lg;
        if (HEAD == 0) {
            lg = coef * q0.x / fmaxf(sqrtf(q0.w), EPSF);
        } else {
            float4 q1 = s4p[1];
            const float w = w_in[roff];
            const float dot  = q0.y + w * (kra - q0.z);
            float nrm2 = q0.w + 2.f * w * (q1.z - q1.x)
                       + w * w * (q1.y + saa - 2.f * q1.w);
            nrm2 = fmaxf(nrm2, 0.f);
            lg = coef * dot / fmaxf(sqrtf(nrm2), EPSF);
        }
        wcs[i] = lg; mL = fmaxf(mL, lg);
        float bb = bias[roff]; ats[i] = bb; mB = fmaxf(mB, bb);
    }
    __syncthreads();
    bred2(mL, mB, true, red);

    float sL = 0.f, sB = 0.f;
    #pragma unroll
    for (int k = 0; k < 8; ++k) {
        int i = tid + k * 256;
        float ew = __expf(wcs[i] - mL);
        float eb = __expf(ats[i] - mB);
        wcs[i] = ew; ats[i] = eb;
        sL += ew; sB += eb;
    }
    bred2(sL, sB, false, red);
    const float iL = 1.0f / sL, iB = 1.0f / sB;

    #pragma unroll
    for (int k = 0; k < 8; ++k) {
        int i = tid + k * 256;
        float wg = g * wcs[i] * iL + (1.0f - g) * ats[i] * iB;
        ats[i] = wg;
    }
    __syncthreads();

    float pv[8]; float ps = 0.f;
    #pragma unroll
    for (int k = 0; k < 8; ++k) {
        int i = tid + k * 256;
        float tw = s0c * ats[(i + NN - 1) & (NN - 1)]
                 + s1c * ats[i]
                 + s2c * ats[(i + 1) & (NN - 1)];
        float p = powf(tw, gamma);
        pv[k] = p; ps += p;
    }
    float dummy = 0.f;
    bred2(ps, dummy, false, red);
    const float inv = 1.0f / (EPSF + ps);
    #pragma unroll
    for (int k = 0; k < 8; ++k) {
        int i = tid + k * 256;
        out[(size_t)b * NN + i] = pv[k] * inv;
    }
}

// ---------------------------------------------------------------------------
// Kernel 4a: partial r = sum_n r_attn * mem over a 256-row chunk (mem
// reconstructed on the fly). Grid BB*8; partials [B,8,64].
// ---------------------------------------------------------------------------
__global__ void __launch_bounds__(256) k_read_partial(const float* __restrict__ mb,
                                                      const float* __restrict__ params,
                                                      const float* __restrict__ wattn,
                                                      const float* __restrict__ rattn,
                                                      float* __restrict__ rpart)
{
    __shared__ float acc_s[32 * 64];

    const int b = blockIdx.x >> 3, chunk = blockIdx.x & 7;
    const int tid = threadIdx.x;
    const int grp = tid >> 3, l8 = tid & 7;
    const float* P = params + (size_t)b * PSTRIDE;

    float ereg[8], areg[8];
    #pragma unroll
    for (int j = 0; j < 8; ++j) { ereg[j] = P[128 + l8 * 8 + j]; areg[j] = P[192 + l8 * 8 + j]; }

    float acc[8];
    #pragma unroll
    for (int j = 0; j < 8; ++j) acc[j] = 0.f;

    #pragma unroll
    for (int it = 0; it < 8; ++it) {
        const int n = chunk * 256 + it * 32 + grp;
        const size_t roff = (size_t)b * NN + n;
        const float w = wattn[roff];
        const float ra = rattn[roff];
        const float4* row = reinterpret_cast<const float4*>(mb + roff * MM);
        float4 v0 = row[2 * l8], v1 = row[2 * l8 + 1];
        float f[8] = {v0.x, v0.y, v0.z, v0.w, v1.x, v1.y, v1.z, v1.w};
        #pragma unroll
        for (int j = 0; j < 8; ++j) {
            float mv = fmaf(f[j], fmaf(-w, ereg[j], 1.0f), w * areg[j]);
            acc[j] = fmaf(ra, mv, acc[j]);
        }
    }
    #pragma unroll
    for (int j = 0; j < 8; ++j) acc_s[grp * 64 + l8 * 8 + j] = acc[j];
    __syncthreads();

    if (tid < 64) {
        float s = 0.f;
        #pragma unroll 8
        for (int g2 = 0; g2 < 32; ++g2) s += acc_s[g2 * 64 + tid];
        rpart[((size_t)b * 8 + chunk) * 64 + tid] = s;
    }
}

// ---------------------------------------------------------------------------
// Kernel 4b: r = sum of 8 partials, out = sigmoid(r@Wo + bo). fp32 out.
// ---------------------------------------------------------------------------
__global__ void __launch_bounds__(64) k_out(const float* __restrict__ rpart,
                                            const float* __restrict__ Wo,
                                            const float* __restrict__ bo,
                                            float* __restrict__ out)
{
    __shared__ float rv[64];
    const int b = blockIdx.x, tid = threadIdx.x;

    float s = 0.f;
    #pragma unroll
    for (int k = 0; k < 8; ++k) s += rpart[((size_t)b * 8 + k) * 64 + tid];
    rv[tid] = s;
    __syncthreads();

    float o = bo[tid];
    #pragma unroll 4
    for (int m = 0; m < 64; ++m) o = fmaf(rv[m], Wo[m * 64 + tid], o);
    out[(size_t)b * 64 + tid] = sigmoidf(o);
}

// ---------------------------------------------------------------------------
extern "C" void kernel_launch(void* const* d_in, const int* in_sizes, int n_in,
                              void* d_out, int out_size, void* d_ws, size_t ws_size,
                              hipStream_t stream)
{
    Ptrs in;
    for (int i = 0; i < 32; ++i) in.p[i] = (const float*)d_in[i];

    float* params = (float*)d_ws;                        // 256*272 floats
    float* bufW  = params + (size_t)BB * PSTRIDE;        // B*N: w_attn
    float* bufR  = bufW + (size_t)BB * NN;               // B*N: r_attn
    float* rpart = bufR + (size_t)BB * NN;               // B*8*64
    float* summ  = rpart + (size_t)BB * 8 * 64;          // B*N*8 row summaries

    const float* mb     = (const float*)d_in[31];
    const float* r_bias = (const float*)d_in[29];
    const float* w_bias = (const float*)d_in[30];

    k_params<<<BB, 256, 0, stream>>>(in, params);
    k_summ<<<BB * 8, 256, 0, stream>>>(mb, params, summ);
    k_combine<0><<<BB, 256, 0, stream>>>(summ, w_bias, params, nullptr, bufW);
    k_combine<1><<<BB, 256, 0, stream>>>(summ, r_bias, params, bufW, bufR);
    k_read_partial<<<BB * 8, 256, 0, stream>>>(mb, params, bufW, bufR, rpart);
    k_out<<<BB, 64, 0, stream>>>(rpart, (const float*)d_in[3], (const float*)d_in[4],
                                 (float*)d_out);
}

// Round 5
// 81.651 us; speedup vs baseline: 1.7550x; 1.0489x over previous
//
#include <hip/hip_runtime.h>
#include <hip/hip_bf16.h>
#include <math.h>

#define BB 256
#define NN 2048
#define MM 64
#define INF_ 128
#define HH 100
#define EPSF 1e-8f
#define PSTRIDE 272

struct Ptrs { const float* p[32]; };

__device__ __forceinline__ float softplusf(float x) {
    return fmaxf(x, 0.0f) + log1pf(__expf(-fabsf(x)));
}
__device__ __forceinline__ float sigmoidf(float x) {
    return 1.0f / (1.0f + __expf(-x));
}

// ---------------------------------------------------------------------------
// Kernel 1: controller h = x@Wc + bc, then all head parameters per batch row.
// Params layout per b (stride PSTRIDE floats):
//  [0..63] k_w   [64..127] k_r   [128..191] e   [192..255] a
//  [256] coef_w = softplus(beta_w)/max(||k_w||,EPS)   [257] coef_r
//  [258] gamma_w  [259] gamma_r  [260] g_w  [261] g_r
//  [262..264] s_w  [265..267] s_r  [268] kra = k_r.a  [269] saa = a.a
// ---------------------------------------------------------------------------
__global__ void __launch_bounds__(256) k_params(Ptrs in, float* __restrict__ params)
{
    __shared__ float xs[INF_];
    __shared__ float hs[HH];
    __shared__ float kws[MM], krs[MM], as_[MM];
    __shared__ float sc[2];

    const int b = blockIdx.x, tid = threadIdx.x;
    const int lane = tid & 63, wv = tid >> 6;

    if (tid < INF_) xs[tid] = in.p[0][b * INF_ + tid];
    __syncthreads();

    if (tid < HH) {
        const float* Wc = in.p[1];
        float acc = in.p[2][tid];
        #pragma unroll 8
        for (int i = 0; i < INF_; ++i)
            acc = fmaf(xs[i], Wc[i * HH + tid], acc);
        hs[tid] = acc;
    }
    __syncthreads();

    float* P = params + (size_t)b * PSTRIDE;

    // four 64-wide heads: wave 0 -> k_w, 1 -> k_r, 2 -> e, 3 -> a
    {
        const int m = lane;
        const float* W; const float* bi;
        if      (wv == 0) { W = in.p[23]; bi = in.p[24]; }
        else if (wv == 1) { W = in.p[13]; bi = in.p[14]; }
        else if (wv == 2) { W = in.p[25]; bi = in.p[26]; }
        else              { W = in.p[27]; bi = in.p[28]; }
        float acc = bi[m];
        #pragma unroll 10
        for (int j = 0; j < HH; ++j)
            acc = fmaf(hs[j], W[j * 64 + m], acc);
        if      (wv == 0) { kws[m] = acc; P[m] = acc; }
        else if (wv == 1) { krs[m] = acc; P[64 + m] = acc; }
        else if (wv == 2) { P[128 + m] = sigmoidf(acc); }
        else              { as_[m] = acc; P[192 + m] = acc; }
    }

    // 12 scalar heads: 3 per wave, full-wave shuffle reduce each
    {
        const float* Wt[3]; int strd;
        if      (wv == 0) { Wt[0] = in.p[15]; Wt[1] = in.p[17]; Wt[2] = in.p[19]; strd = 1; }
        else if (wv == 1) { Wt[0] = in.p[5];  Wt[1] = in.p[7];  Wt[2] = in.p[9];  strd = 1; }
        else if (wv == 2) { Wt[0] = in.p[21]; Wt[1] = in.p[21]; Wt[2] = in.p[21]; strd = 3; }
        else              { Wt[0] = in.p[11]; Wt[1] = in.p[11]; Wt[2] = in.p[11]; strd = 3; }

        #pragma unroll
        for (int sidx = 0; sidx < 3; ++sidx) {
            const float* W = Wt[sidx];
            const int off = (strd == 3) ? sidx : 0;
            float v = 0.f;
            if (lane < HH)      v = hs[lane] * W[lane * strd + off];
            if (lane < HH - 64) v = fmaf(hs[lane + 64], W[(lane + 64) * strd + off], v);
            #pragma unroll
            for (int m2 = 32; m2; m2 >>= 1) v += __shfl_xor(v, m2);
            if (lane == 0) {
                if (wv == 0) {
                    if      (sidx == 0) sc[0]  = softplusf(v + in.p[16][0]);
                    else if (sidx == 1) P[258] = 1.0f + softplusf(v + in.p[18][0]);
                    else                P[260] = sigmoidf(v + in.p[20][0]);
                } else if (wv == 1) {
                    if      (sidx == 0) sc[1]  = softplusf(v + in.p[6][0]);
                    else if (sidx == 1) P[259] = 1.0f + softplusf(v + in.p[8][0]);
                    else                P[261] = sigmoidf(v + in.p[10][0]);
                } else if (wv == 2) {
                    P[262 + sidx] = v + in.p[22][sidx];
                } else {
                    P[265 + sidx] = v + in.p[12][sidx];
                }
            }
        }
    }
    __syncthreads();

    if (wv == 0) {
        float v = kws[lane] * kws[lane];
        #pragma unroll
        for (int m2 = 32; m2; m2 >>= 1) v += __shfl_xor(v, m2);
        if (lane == 0) P[256] = sc[0] / fmaxf(sqrtf(v), EPSF);
    }
    if (wv == 1) {
        float v = krs[lane] * krs[lane];
        #pragma unroll
        for (int m2 = 32; m2; m2 >>= 1) v += __shfl_xor(v, m2);
        if (lane == 0) P[257] = sc[1] / fmaxf(sqrtf(v), EPSF);
    }
    if (wv == 2) {
        float v = krs[lane] * as_[lane];
        #pragma unroll
        for (int m2 = 32; m2; m2 >>= 1) v += __shfl_xor(v, m2);
        if (lane == 0) P[268] = v;
    }
    if (wv == 3) {
        float v = as_[lane] * as_[lane];
        #pragma unroll
        for (int m2 = 32; m2; m2 >>= 1) v += __shfl_xor(v, m2);
        if (lane == 0) P[269] = v;
    }
}

// ---------------------------------------------------------------------------
// Kernel 2: single pass over memory_bias computing 8 row-summaries:
//  [0]=lw (k_w.mb)  [1]=d1 (k_r.mb)  [2]=d2 ((k_r e).mb)  [3]=s0 (mb^2)
//  [4]=s1 (mb^2 e)  [5]=s2 (mb^2 e^2) [6]=s3 (mb.a)       [7]=s4 (mb.(e a))
// ---------------------------------------------------------------------------
__global__ void __launch_bounds__(256) k_summ(const float* __restrict__ mb,
                                              const float* __restrict__ params,
                                              float* __restrict__ summ)
{
    const int b = blockIdx.x >> 3, chunk = blockIdx.x & 7;
    const int tid = threadIdx.x;
    const int grp = tid >> 3, l8 = tid & 7;
    const float* P = params + (size_t)b * PSTRIDE;

    float kw[8], kr[8], kre[8], ev[8], ee[8], av[8], ea[8];
    #pragma unroll
    for (int j = 0; j < 8; ++j) {
        kw[j] = P[l8 * 8 + j];
        kr[j] = P[64 + l8 * 8 + j];
        ev[j] = P[128 + l8 * 8 + j];
        av[j] = P[192 + l8 * 8 + j];
        kre[j] = kr[j] * ev[j];
        ee[j]  = ev[j] * ev[j];
        ea[j]  = ev[j] * av[j];
    }

    #pragma unroll
    for (int it = 0; it < 8; ++it) {
        const int n = chunk * 256 + it * 32 + grp;
        const size_t roff = (size_t)b * NN + n;
        const float4* row = reinterpret_cast<const float4*>(mb + roff * MM);
        float4 v0 = row[2 * l8], v1 = row[2 * l8 + 1];
        float f[8] = {v0.x, v0.y, v0.z, v0.w, v1.x, v1.y, v1.z, v1.w};

        float acc[8];
        #pragma unroll
        for (int j = 0; j < 8; ++j) acc[j] = 0.f;
        #pragma unroll
        for (int j = 0; j < 8; ++j) {
            const float m = f[j], m2 = m * m;
            acc[0] = fmaf(kw[j],  m,  acc[0]);
            acc[1] = fmaf(kr[j],  m,  acc[1]);
            acc[2] = fmaf(kre[j], m,  acc[2]);
            acc[3] += m2;
            acc[4] = fmaf(ev[j],  m2, acc[4]);
            acc[5] = fmaf(ee[j],  m2, acc[5]);
            acc[6] = fmaf(av[j],  m,  acc[6]);
            acc[7] = fmaf(ea[j],  m,  acc[7]);
        }

        // transposing butterfly over the 8-lane group: lane l8 ends with acc[l8]
        float k1[4];
        #pragma unroll
        for (int k = 0; k < 4; ++k) {
            float snd = (l8 & 1) ? acc[2 * k] : acc[2 * k + 1];
            float rcv = __shfl_xor(snd, 1);
            k1[k] = ((l8 & 1) ? acc[2 * k + 1] : acc[2 * k]) + rcv;
        }
        float k2[2];
        #pragma unroll
        for (int k = 0; k < 2; ++k) {
            float snd = (l8 & 2) ? k1[2 * k] : k1[2 * k + 1];
            float rcv = __shfl_xor(snd, 2);
            k2[k] = ((l8 & 2) ? k1[2 * k + 1] : k1[2 * k]) + rcv;
        }
        {
            float snd = (l8 & 4) ? k2[0] : k2[1];
            float rcv = __shfl_xor(snd, 4);
            float tot = ((l8 & 4) ? k2[1] : k2[0]) + rcv;
            summ[roff * 8 + l8] = tot;
        }
    }
}

// ---------------------------------------------------------------------------
// Block reduction over 256 threads (4 waves), two values at once.
// ---------------------------------------------------------------------------
__device__ __forceinline__ void bred2(float& a, float& b, bool ismax, float* red)
{
    #pragma unroll
    for (int m = 32; m; m >>= 1) {
        float ta = __shfl_xor(a, m), tb = __shfl_xor(b, m);
        if (ismax) { a = fmaxf(a, ta); b = fmaxf(b, tb); }
        else       { a += ta; b += tb; }
    }
    const int wid = threadIdx.x >> 6;
    if ((threadIdx.x & 63) == 0) { red[wid] = a; red[4 + wid] = b; }
    __syncthreads();
    float ra = red[0], rb = red[4];
    for (int w = 1; w < 4; ++w) {
        if (ismax) { ra = fmaxf(ra, red[w]); rb = fmaxf(rb, red[4 + w]); }
        else       { ra += red[w]; rb += red[4 + w]; }
    }
    __syncthreads();
    a = ra; b = rb;
}

// ---------------------------------------------------------------------------
// Kernel 3: BOTH heads fused (one block per b). Head 0 (write): logits from
// summaries -> softmax/interp/conv/sharpen -> w_attn (registers + global).
// Head 1 (read): logits algebraically from summaries + w_attn -> same
// pipeline -> r_attn. No inter-kernel round trip.
// ---------------------------------------------------------------------------
__global__ void __launch_bounds__(256) k_combine2(const float* __restrict__ summ,
                                                  const float* __restrict__ w_bias,
                                                  const float* __restrict__ r_bias,
                                                  const float* __restrict__ params,
                                                  float* __restrict__ bufW,
                                                  float* __restrict__ bufR)
{
    __shared__ float wcs[NN];
    __shared__ float ats[NN];
    __shared__ float red[8];

    const int b = blockIdx.x, tid = threadIdx.x;
    const float* P = params + (size_t)b * PSTRIDE;
    const float kra = P[268], saa = P[269];

    float wreg[8];

    // ================= head 0 (write) =================
    {
        const float g = P[260], gamma = P[258];
        const float s0c = P[262], s1c = P[263], s2c = P[264];
        const float coef = P[256];

        float mL = -1e30f, mB = -1e30f;
        #pragma unroll
        for (int k = 0; k < 8; ++k) {
            int i = tid + k * 256;
            const size_t roff = (size_t)b * NN + i;
            const float4 q0 = reinterpret_cast<const float4*>(summ + roff * 8)[0];
            float lg = coef * q0.x / fmaxf(sqrtf(q0.w), EPSF);
            wcs[i] = lg; mL = fmaxf(mL, lg);
            float bb = w_bias[roff]; ats[i] = bb; mB = fmaxf(mB, bb);
        }
        __syncthreads();
        bred2(mL, mB, true, red);

        float sL = 0.f, sB = 0.f;
        #pragma unroll
        for (int k = 0; k < 8; ++k) {
            int i = tid + k * 256;
            float ew = __expf(wcs[i] - mL);
            float eb = __expf(ats[i] - mB);
            wcs[i] = ew; ats[i] = eb;
            sL += ew; sB += eb;
        }
        bred2(sL, sB, false, red);
        const float iL = 1.0f / sL, iB = 1.0f / sB;

        #pragma unroll
        for (int k = 0; k < 8; ++k) {
            int i = tid + k * 256;
            ats[i] = g * wcs[i] * iL + (1.0f - g) * ats[i] * iB;
        }
        __syncthreads();

        float pv[8]; float ps = 0.f;
        #pragma unroll
        for (int k = 0; k < 8; ++k) {
            int i = tid + k * 256;
            float tw = s0c * ats[(i + NN - 1) & (NN - 1)]
                     + s1c * ats[i]
                     + s2c * ats[(i + 1) & (NN - 1)];
            float p = powf(tw, gamma);
            pv[k] = p; ps += p;
        }
        float dummy = 0.f;
        bred2(ps, dummy, false, red);
        const float inv = 1.0f / (EPSF + ps);
        #pragma unroll
        for (int k = 0; k < 8; ++k) {
            int i = tid + k * 256;
            float w = pv[k] * inv;
            wreg[k] = w;
            bufW[(size_t)b * NN + i] = w;
        }
        __syncthreads();   // ats/wcs about to be reused
    }

    // ================= head 1 (read) =================
    {
        const float g = P[261], gamma = P[259];
        const float s0c = P[265], s1c = P[266], s2c = P[267];
        const float coef = P[257];

        float mL = -1e30f, mB = -1e30f;
        #pragma unroll
        for (int k = 0; k < 8; ++k) {
            int i = tid + k * 256;
            const size_t roff = (size_t)b * NN + i;
            const float4* s4p = reinterpret_cast<const float4*>(summ + roff * 8);
            const float4 q0 = s4p[0];
            const float4 q1 = s4p[1];
            const float w = wreg[k];
            const float dot = q0.y + w * (kra - q0.z);
            float nrm2 = q0.w + 2.f * w * (q1.z - q1.x)
                       + w * w * (q1.y + saa - 2.f * q1.w);
            nrm2 = fmaxf(nrm2, 0.f);
            float lg = coef * dot / fmaxf(sqrtf(nrm2), EPSF);
            wcs[i] = lg; mL = fmaxf(mL, lg);
            float bb = r_bias[roff]; ats[i] = bb; mB = fmaxf(mB, bb);
        }
        __syncthreads();
        bred2(mL, mB, true, red);

        float sL = 0.f, sB = 0.f;
        #pragma unroll
        for (int k = 0; k < 8; ++k) {
            int i = tid + k * 256;
            float ew = __expf(wcs[i] - mL);
            float eb = __expf(ats[i] - mB);
            wcs[i] = ew; ats[i] = eb;
            sL += ew; sB += eb;
        }
        bred2(sL, sB, false, red);
        const float iL = 1.0f / sL, iB = 1.0f / sB;

        #pragma unroll
        for (int k = 0; k < 8; ++k) {
            int i = tid + k * 256;
            ats[i] = g * wcs[i] * iL + (1.0f - g) * ats[i] * iB;
        }
        __syncthreads();

        float pv[8]; float ps = 0.f;
        #pragma unroll
        for (int k = 0; k < 8; ++k) {
            int i = tid + k * 256;
            float tw = s0c * ats[(i + NN - 1) & (NN - 1)]
                     + s1c * ats[i]
                     + s2c * ats[(i + 1) & (NN - 1)];
            float p = powf(tw, gamma);
            pv[k] = p; ps += p;
        }
        float dummy = 0.f;
        bred2(ps, dummy, false, red);
        const float inv = 1.0f / (EPSF + ps);
        #pragma unroll
        for (int k = 0; k < 8; ++k) {
            int i = tid + k * 256;
            bufR[(size_t)b * NN + i] = pv[k] * inv;
        }
    }
}

// ---------------------------------------------------------------------------
// Kernel 4: one block (512 thr) per b. r = sum_n r_attn * mem (reconstructed),
// group-shuffle reduction, then out = sigmoid(r@Wo + bo). No global partials.
// ---------------------------------------------------------------------------
__global__ void __launch_bounds__(512) k_read_out(const float* __restrict__ mb,
                                                  const float* __restrict__ params,
                                                  const float* __restrict__ wattn,
                                                  const float* __restrict__ rattn,
                                                  const float* __restrict__ Wo,
                                                  const float* __restrict__ bo,
                                                  float* __restrict__ out)
{
    __shared__ float wpart[8 * 64];
    __shared__ float rv[64];

    const int b = blockIdx.x, tid = threadIdx.x;
    const int grp = tid >> 3, l8 = tid & 7;     // grp 0..63
    const int lane = tid & 63, wv = tid >> 6;   // 8 waves
    const float* P = params + (size_t)b * PSTRIDE;

    float ereg[8], areg[8];
    #pragma unroll
    for (int j = 0; j < 8; ++j) { ereg[j] = P[128 + l8 * 8 + j]; areg[j] = P[192 + l8 * 8 + j]; }

    float acc[8];
    #pragma unroll
    for (int j = 0; j < 8; ++j) acc[j] = 0.f;

    #pragma unroll 4
    for (int it = 0; it < 32; ++it) {
        const int n = it * 64 + grp;
        const size_t roff = (size_t)b * NN + n;
        const float w = wattn[roff];
        const float ra = rattn[roff];
        const float4* row = reinterpret_cast<const float4*>(mb + roff * MM);
        float4 v0 = row[2 * l8], v1 = row[2 * l8 + 1];
        float f[8] = {v0.x, v0.y, v0.z, v0.w, v1.x, v1.y, v1.z, v1.w};
        #pragma unroll
        for (int j = 0; j < 8; ++j) {
            float mv = fmaf(f[j], fmaf(-w, ereg[j], 1.0f), w * areg[j]);
            acc[j] = fmaf(ra, mv, acc[j]);
        }
    }

    // reduce across the 8 groups within each wave (lane = grpLocal*8 + l8)
    #pragma unroll
    for (int j = 0; j < 8; ++j) {
        #pragma unroll
        for (int mask = 8; mask < 64; mask <<= 1)
            acc[j] += __shfl_xor(acc[j], mask);
    }
    if (lane < 8) {              // grpLocal==0 lanes: l8 = lane
        #pragma unroll
        for (int j = 0; j < 8; ++j) wpart[wv * 64 + lane * 8 + j] = acc[j];
    }
    __syncthreads();

    if (tid < 64) {
        float s = 0.f;
        #pragma unroll
        for (int w8 = 0; w8 < 8; ++w8) s += wpart[w8 * 64 + tid];
        rv[tid] = s;
    }
    __syncthreads();

    if (tid < 64) {
        float o = bo[tid];
        #pragma unroll 4
        for (int m = 0; m < 64; ++m) o = fmaf(rv[m], Wo[m * 64 + tid], o);
        out[(size_t)b * 64 + tid] = sigmoidf(o);
    }
}

// ---------------------------------------------------------------------------
extern "C" void kernel_launch(void* const* d_in, const int* in_sizes, int n_in,
                              void* d_out, int out_size, void* d_ws, size_t ws_size,
                              hipStream_t stream)
{
    Ptrs in;
    for (int i = 0; i < 32; ++i) in.p[i] = (const float*)d_in[i];

    float* params = (float*)d_ws;                        // 256*272 floats
    float* bufW  = params + (size_t)BB * PSTRIDE;        // B*N: w_attn
    float* bufR  = bufW + (size_t)BB * NN;               // B*N: r_attn
    float* summ  = bufR + (size_t)BB * NN;               // B*N*8 row summaries

    const float* mb     = (const float*)d_in[31];
    const float* r_bias = (const float*)d_in[29];
    const float* w_bias = (const float*)d_in[30];

    k_params<<<BB, 256, 0, stream>>>(in, params);
    k_summ<<<BB * 8, 256, 0, stream>>>(mb, params, summ);
    k_combine2<<<BB, 256, 0, stream>>>(summ, w_bias, r_bias, params, bufW, bufR);
    k_read_out<<<BB, 512, 0, stream>>>(mb, params, bufW, bufR,
                                       (const float*)d_in[3], (const float*)d_in[4],
                                       (float*)d_out);
}

// Round 6
// 77.303 us; speedup vs baseline: 1.8537x; 1.0562x over previous
//
#include <hip/hip_runtime.h>
#include <hip/hip_bf16.h>
#include <math.h>

#define BB 256
#define NN 2048
#define MM 64
#define INF_ 128
#define HH 100
#define EPSF 1e-8f
#define PSTRIDE 272

struct Ptrs { const float* p[32]; };

__device__ __forceinline__ float softplusf(float x) {
    return fmaxf(x, 0.0f) + log1pf(__expf(-fabsf(x)));
}
__device__ __forceinline__ float sigmoidf(float x) {
    return 1.0f / (1.0f + __expf(-x));
}
// fast positive-base pow; |rel err| ~1e-6, far under the 1.36e-2 threshold
__device__ __forceinline__ float fpowf(float x, float g) {
    return __expf(g * __logf(x));
}

// ---------------------------------------------------------------------------
// Kernel 1: controller h = x@Wc + bc, then all head parameters per batch row.
// Params layout per b (stride PSTRIDE floats):
//  [0..63] k_w   [64..127] k_r   [128..191] e   [192..255] a
//  [256] coef_w = softplus(beta_w)/max(||k_w||,EPS)   [257] coef_r
//  [258] gamma_w  [259] gamma_r  [260] g_w  [261] g_r
//  [262..264] s_w  [265..267] s_r  [268] kra = k_r.a  [269] saa = a.a
// ---------------------------------------------------------------------------
__global__ void __launch_bounds__(256) k_params(Ptrs in, float* __restrict__ params)
{
    __shared__ float xs[INF_];
    __shared__ float hs[HH];
    __shared__ float kws[MM], krs[MM], as_[MM];
    __shared__ float sc[2];

    const int b = blockIdx.x, tid = threadIdx.x;
    const int lane = tid & 63, wv = tid >> 6;

    if (tid < INF_) xs[tid] = in.p[0][b * INF_ + tid];
    __syncthreads();

    if (tid < HH) {
        const float* Wc = in.p[1];
        float acc = in.p[2][tid];
        #pragma unroll 8
        for (int i = 0; i < INF_; ++i)
            acc = fmaf(xs[i], Wc[i * HH + tid], acc);
        hs[tid] = acc;
    }
    __syncthreads();

    float* P = params + (size_t)b * PSTRIDE;

    // four 64-wide heads: wave 0 -> k_w, 1 -> k_r, 2 -> e, 3 -> a
    {
        const int m = lane;
        const float* W; const float* bi;
        if      (wv == 0) { W = in.p[23]; bi = in.p[24]; }
        else if (wv == 1) { W = in.p[13]; bi = in.p[14]; }
        else if (wv == 2) { W = in.p[25]; bi = in.p[26]; }
        else              { W = in.p[27]; bi = in.p[28]; }
        float acc = bi[m];
        #pragma unroll 10
        for (int j = 0; j < HH; ++j)
            acc = fmaf(hs[j], W[j * 64 + m], acc);
        if      (wv == 0) { kws[m] = acc; P[m] = acc; }
        else if (wv == 1) { krs[m] = acc; P[64 + m] = acc; }
        else if (wv == 2) { P[128 + m] = sigmoidf(acc); }
        else              { as_[m] = acc; P[192 + m] = acc; }
    }

    // 12 scalar heads: 3 per wave, full-wave shuffle reduce each
    {
        const float* Wt[3]; int strd;
        if      (wv == 0) { Wt[0] = in.p[15]; Wt[1] = in.p[17]; Wt[2] = in.p[19]; strd = 1; }
        else if (wv == 1) { Wt[0] = in.p[5];  Wt[1] = in.p[7];  Wt[2] = in.p[9];  strd = 1; }
        else if (wv == 2) { Wt[0] = in.p[21]; Wt[1] = in.p[21]; Wt[2] = in.p[21]; strd = 3; }
        else              { Wt[0] = in.p[11]; Wt[1] = in.p[11]; Wt[2] = in.p[11]; strd = 3; }

        #pragma unroll
        for (int sidx = 0; sidx < 3; ++sidx) {
            const float* W = Wt[sidx];
            const int off = (strd == 3) ? sidx : 0;
            float v = 0.f;
            if (lane < HH)      v = hs[lane] * W[lane * strd + off];
            if (lane < HH - 64) v = fmaf(hs[lane + 64], W[(lane + 64) * strd + off], v);
            #pragma unroll
            for (int m2 = 32; m2; m2 >>= 1) v += __shfl_xor(v, m2);
            if (lane == 0) {
                if (wv == 0) {
                    if      (sidx == 0) sc[0]  = softplusf(v + in.p[16][0]);
                    else if (sidx == 1) P[258] = 1.0f + softplusf(v + in.p[18][0]);
                    else                P[260] = sigmoidf(v + in.p[20][0]);
                } else if (wv == 1) {
                    if      (sidx == 0) sc[1]  = softplusf(v + in.p[6][0]);
                    else if (sidx == 1) P[259] = 1.0f + softplusf(v + in.p[8][0]);
                    else                P[261] = sigmoidf(v + in.p[10][0]);
                } else if (wv == 2) {
                    P[262 + sidx] = v + in.p[22][sidx];
                } else {
                    P[265 + sidx] = v + in.p[12][sidx];
                }
            }
        }
    }
    __syncthreads();

    if (wv == 0) {
        float v = kws[lane] * kws[lane];
        #pragma unroll
        for (int m2 = 32; m2; m2 >>= 1) v += __shfl_xor(v, m2);
        if (lane == 0) P[256] = sc[0] / fmaxf(sqrtf(v), EPSF);
    }
    if (wv == 1) {
        float v = krs[lane] * krs[lane];
        #pragma unroll
        for (int m2 = 32; m2; m2 >>= 1) v += __shfl_xor(v, m2);
        if (lane == 0) P[257] = sc[1] / fmaxf(sqrtf(v), EPSF);
    }
    if (wv == 2) {
        float v = krs[lane] * as_[lane];
        #pragma unroll
        for (int m2 = 32; m2; m2 >>= 1) v += __shfl_xor(v, m2);
        if (lane == 0) P[268] = v;
    }
    if (wv == 3) {
        float v = as_[lane] * as_[lane];
        #pragma unroll
        for (int m2 = 32; m2; m2 >>= 1) v += __shfl_xor(v, m2);
        if (lane == 0) P[269] = v;
    }
}

// ---------------------------------------------------------------------------
// Kernel 2: single pass over memory_bias computing 8 row-summaries:
//  [0]=lw (k_w.mb)  [1]=d1 (k_r.mb)  [2]=d2 ((k_r e).mb)  [3]=s0 (mb^2)
//  [4]=s1 (mb^2 e)  [5]=s2 (mb^2 e^2) [6]=s3 (mb.a)       [7]=s4 (mb.(e a))
// ---------------------------------------------------------------------------
__global__ void __launch_bounds__(256) k_summ(const float* __restrict__ mb,
                                              const float* __restrict__ params,
                                              float* __restrict__ summ)
{
    const int b = blockIdx.x >> 3, chunk = blockIdx.x & 7;
    const int tid = threadIdx.x;
    const int grp = tid >> 3, l8 = tid & 7;
    const float* P = params + (size_t)b * PSTRIDE;

    float kw[8], kr[8], kre[8], ev[8], ee[8], av[8], ea[8];
    #pragma unroll
    for (int j = 0; j < 8; ++j) {
        kw[j] = P[l8 * 8 + j];
        kr[j] = P[64 + l8 * 8 + j];
        ev[j] = P[128 + l8 * 8 + j];
        av[j] = P[192 + l8 * 8 + j];
        kre[j] = kr[j] * ev[j];
        ee[j]  = ev[j] * ev[j];
        ea[j]  = ev[j] * av[j];
    }

    #pragma unroll
    for (int it = 0; it < 8; ++it) {
        const int n = chunk * 256 + it * 32 + grp;
        const size_t roff = (size_t)b * NN + n;
        const float4* row = reinterpret_cast<const float4*>(mb + roff * MM);
        float4 v0 = row[2 * l8], v1 = row[2 * l8 + 1];
        float f[8] = {v0.x, v0.y, v0.z, v0.w, v1.x, v1.y, v1.z, v1.w};

        float acc[8];
        #pragma unroll
        for (int j = 0; j < 8; ++j) acc[j] = 0.f;
        #pragma unroll
        for (int j = 0; j < 8; ++j) {
            const float m = f[j], m2 = m * m;
            acc[0] = fmaf(kw[j],  m,  acc[0]);
            acc[1] = fmaf(kr[j],  m,  acc[1]);
            acc[2] = fmaf(kre[j], m,  acc[2]);
            acc[3] += m2;
            acc[4] = fmaf(ev[j],  m2, acc[4]);
            acc[5] = fmaf(ee[j],  m2, acc[5]);
            acc[6] = fmaf(av[j],  m,  acc[6]);
            acc[7] = fmaf(ea[j],  m,  acc[7]);
        }

        // transposing butterfly over the 8-lane group: lane l8 ends with acc[l8]
        float k1[4];
        #pragma unroll
        for (int k = 0; k < 4; ++k) {
            float snd = (l8 & 1) ? acc[2 * k] : acc[2 * k + 1];
            float rcv = __shfl_xor(snd, 1);
            k1[k] = ((l8 & 1) ? acc[2 * k + 1] : acc[2 * k]) + rcv;
        }
        float k2[2];
        #pragma unroll
        for (int k = 0; k < 2; ++k) {
            float snd = (l8 & 2) ? k1[2 * k] : k1[2 * k + 1];
            float rcv = __shfl_xor(snd, 2);
            k2[k] = ((l8 & 2) ? k1[2 * k + 1] : k1[2 * k]) + rcv;
        }
        {
            float snd = (l8 & 4) ? k2[0] : k2[1];
            float rcv = __shfl_xor(snd, 4);
            float tot = ((l8 & 4) ? k2[1] : k2[0]) + rcv;
            summ[roff * 8 + l8] = tot;
        }
    }
}

// ---------------------------------------------------------------------------
// Block reduction over 512 threads (8 waves), two values at once.
// ---------------------------------------------------------------------------
__device__ __forceinline__ void bred2_8(float& a, float& b, bool ismax, float* red)
{
    #pragma unroll
    for (int m = 32; m; m >>= 1) {
        float ta = __shfl_xor(a, m), tb = __shfl_xor(b, m);
        if (ismax) { a = fmaxf(a, ta); b = fmaxf(b, tb); }
        else       { a += ta; b += tb; }
    }
    const int wid = threadIdx.x >> 6;
    if ((threadIdx.x & 63) == 0) { red[wid] = a; red[8 + wid] = b; }
    __syncthreads();
    float ra = red[0], rb = red[8];
    #pragma unroll
    for (int w = 1; w < 8; ++w) {
        if (ismax) { ra = fmaxf(ra, red[w]); rb = fmaxf(rb, red[8 + w]); }
        else       { ra += red[w]; rb += red[8 + w]; }
    }
    __syncthreads();
    a = ra; b = rb;
}

// ---------------------------------------------------------------------------
// Kernel 3: both heads fused, 512 threads (4 elems/thread). Head 0: logits
// from summaries -> softmax/interp/conv/sharpen -> w_attn. Head 1: logits
// algebraically from summaries + w_attn (registers) -> same -> r_attn.
// ---------------------------------------------------------------------------
__global__ void __launch_bounds__(512) k_combine2(const float* __restrict__ summ,
                                                  const float* __restrict__ w_bias,
                                                  const float* __restrict__ r_bias,
                                                  const float* __restrict__ params,
                                                  float* __restrict__ bufW,
                                                  float* __restrict__ bufR)
{
    __shared__ float wcs[NN];
    __shared__ float ats[NN];
    __shared__ float red[16];

    const int b = blockIdx.x, tid = threadIdx.x;
    const float* P = params + (size_t)b * PSTRIDE;
    const float kra = P[268], saa = P[269];

    float wreg[4], q0y[4], q0z[4], q0w[4];

    // ================= head 0 (write) =================
    {
        const float g = P[260], gamma = P[258];
        const float s0c = P[262], s1c = P[263], s2c = P[264];
        const float coef = P[256];

        float mL = -1e30f, mB = -1e30f;
        #pragma unroll
        for (int k = 0; k < 4; ++k) {
            int i = tid + k * 512;
            const size_t roff = (size_t)b * NN + i;
            const float4 q0 = reinterpret_cast<const float4*>(summ + roff * 8)[0];
            q0y[k] = q0.y; q0z[k] = q0.z; q0w[k] = q0.w;
            float lg = coef * q0.x / fmaxf(sqrtf(q0.w), EPSF);
            wcs[i] = lg; mL = fmaxf(mL, lg);
            float bb = w_bias[roff]; ats[i] = bb; mB = fmaxf(mB, bb);
        }
        __syncthreads();
        bred2_8(mL, mB, true, red);

        float sL = 0.f, sB = 0.f;
        #pragma unroll
        for (int k = 0; k < 4; ++k) {
            int i = tid + k * 512;
            float ew = __expf(wcs[i] - mL);
            float eb = __expf(ats[i] - mB);
            wcs[i] = ew; ats[i] = eb;
            sL += ew; sB += eb;
        }
        bred2_8(sL, sB, false, red);
        const float iL = 1.0f / sL, iB = 1.0f / sB;

        #pragma unroll
        for (int k = 0; k < 4; ++k) {
            int i = tid + k * 512;
            ats[i] = g * wcs[i] * iL + (1.0f - g) * ats[i] * iB;
        }
        __syncthreads();

        float pv[4]; float ps = 0.f;
        #pragma unroll
        for (int k = 0; k < 4; ++k) {
            int i = tid + k * 512;
            float tw = s0c * ats[(i + NN - 1) & (NN - 1)]
                     + s1c * ats[i]
                     + s2c * ats[(i + 1) & (NN - 1)];
            float p = fpowf(tw, gamma);
            pv[k] = p; ps += p;
        }
        float dummy = 0.f;
        bred2_8(ps, dummy, false, red);
        const float inv = 1.0f / (EPSF + ps);
        #pragma unroll
        for (int k = 0; k < 4; ++k) {
            int i = tid + k * 512;
            float w = pv[k] * inv;
            wreg[k] = w;
            bufW[(size_t)b * NN + i] = w;
        }
        __syncthreads();   // ats/wcs about to be reused
    }

    // ================= head 1 (read) =================
    {
        const float g = P[261], gamma = P[259];
        const float s0c = P[265], s1c = P[266], s2c = P[267];
        const float coef = P[257];

        float mL = -1e30f, mB = -1e30f;
        #pragma unroll
        for (int k = 0; k < 4; ++k) {
            int i = tid + k * 512;
            const size_t roff = (size_t)b * NN + i;
            const float4 q1 = reinterpret_cast<const float4*>(summ + roff * 8)[1];
            const float w = wreg[k];
            const float dot = q0y[k] + w * (kra - q0z[k]);
            float nrm2 = q0w[k] + 2.f * w * (q1.z - q1.x)
                       + w * w * (q1.y + saa - 2.f * q1.w);
            nrm2 = fmaxf(nrm2, 0.f);
            float lg = coef * dot / fmaxf(sqrtf(nrm2), EPSF);
            wcs[i] = lg; mL = fmaxf(mL, lg);
            float bb = r_bias[roff]; ats[i] = bb; mB = fmaxf(mB, bb);
        }
        __syncthreads();
        bred2_8(mL, mB, true, red);

        float sL = 0.f, sB = 0.f;
        #pragma unroll
        for (int k = 0; k < 4; ++k) {
            int i = tid + k * 512;
            float ew = __expf(wcs[i] - mL);
            float eb = __expf(ats[i] - mB);
            wcs[i] = ew; ats[i] = eb;
            sL += ew; sB += eb;
        }
        bred2_8(sL, sB, false, red);
        const float iL = 1.0f / sL, iB = 1.0f / sB;

        #pragma unroll
        for (int k = 0; k < 4; ++k) {
            int i = tid + k * 512;
            ats[i] = g * wcs[i] * iL + (1.0f - g) * ats[i] * iB;
        }
        __syncthreads();

        float pv[4]; float ps = 0.f;
        #pragma unroll
        for (int k = 0; k < 4; ++k) {
            int i = tid + k * 512;
            float tw = s0c * ats[(i + NN - 1) & (NN - 1)]
                     + s1c * ats[i]
                     + s2c * ats[(i + 1) & (NN - 1)];
            float p = fpowf(tw, gamma);
            pv[k] = p; ps += p;
        }
        float dummy = 0.f;
        bred2_8(ps, dummy, false, red);
        const float inv = 1.0f / (EPSF + ps);
        #pragma unroll
        for (int k = 0; k < 4; ++k) {
            int i = tid + k * 512;
            bufR[(size_t)b * NN + i] = pv[k] * inv;
        }
    }
}

// ---------------------------------------------------------------------------
// Kernel 4a: partial r = sum_n r_attn * mem over a 512-row chunk (mem
// reconstructed on the fly). Grid BB*4, 256 thr; partials [B,4,64].
// ---------------------------------------------------------------------------
__global__ void __launch_bounds__(256) k_read_partial(const float* __restrict__ mb,
                                                      const float* __restrict__ params,
                                                      const float* __restrict__ wattn,
                                                      const float* __restrict__ rattn,
                                                      float* __restrict__ rpart)
{
    __shared__ float acc_s[32 * 64];

    const int b = blockIdx.x >> 2, chunk = blockIdx.x & 3;
    const int tid = threadIdx.x;
    const int grp = tid >> 3, l8 = tid & 7;
    const float* P = params + (size_t)b * PSTRIDE;

    float ereg[8], areg[8];
    #pragma unroll
    for (int j = 0; j < 8; ++j) { ereg[j] = P[128 + l8 * 8 + j]; areg[j] = P[192 + l8 * 8 + j]; }

    float acc[8];
    #pragma unroll
    for (int j = 0; j < 8; ++j) acc[j] = 0.f;

    #pragma unroll 8
    for (int it = 0; it < 16; ++it) {
        const int n = chunk * 512 + it * 32 + grp;
        const size_t roff = (size_t)b * NN + n;
        const float w = wattn[roff];
        const float ra = rattn[roff];
        const float4* row = reinterpret_cast<const float4*>(mb + roff * MM);
        float4 v0 = row[2 * l8], v1 = row[2 * l8 + 1];
        float f[8] = {v0.x, v0.y, v0.z, v0.w, v1.x, v1.y, v1.z, v1.w};
        #pragma unroll
        for (int j = 0; j < 8; ++j) {
            float mv = fmaf(f[j], fmaf(-w, ereg[j], 1.0f), w * areg[j]);
            acc[j] = fmaf(ra, mv, acc[j]);
        }
    }
    #pragma unroll
    for (int j = 0; j < 8; ++j) acc_s[grp * 64 + l8 * 8 + j] = acc[j];
    __syncthreads();

    if (tid < 64) {
        float s = 0.f;
        #pragma unroll 8
        for (int g2 = 0; g2 < 32; ++g2) s += acc_s[g2 * 64 + tid];
        rpart[((size_t)b * 4 + chunk) * 64 + tid] = s;
    }
}

// ---------------------------------------------------------------------------
// Kernel 4b: r = sum of 4 partials, out = sigmoid(r@Wo + bo). fp32 out.
// ---------------------------------------------------------------------------
__global__ void __launch_bounds__(64) k_out(const float* __restrict__ rpart,
                                            const float* __restrict__ Wo,
                                            const float* __restrict__ bo,
                                            float* __restrict__ out)
{
    __shared__ float rv[64];
    const int b = blockIdx.x, tid = threadIdx.x;

    float s = 0.f;
    #pragma unroll
    for (int k = 0; k < 4; ++k) s += rpart[((size_t)b * 4 + k) * 64 + tid];
    rv[tid] = s;
    __syncthreads();

    float o = bo[tid];
    #pragma unroll 4
    for (int m = 0; m < 64; ++m) o = fmaf(rv[m], Wo[m * 64 + tid], o);
    out[(size_t)b * 64 + tid] = sigmoidf(o);
}

// ---------------------------------------------------------------------------
extern "C" void kernel_launch(void* const* d_in, const int* in_sizes, int n_in,
                              void* d_out, int out_size, void* d_ws, size_t ws_size,
                              hipStream_t stream)
{
    Ptrs in;
    for (int i = 0; i < 32; ++i) in.p[i] = (const float*)d_in[i];

    float* params = (float*)d_ws;                        // 256*272 floats
    float* bufW  = params + (size_t)BB * PSTRIDE;        // B*N: w_attn
    float* bufR  = bufW + (size_t)BB * NN;               // B*N: r_attn
    float* rpart = bufR + (size_t)BB * NN;               // B*4*64
    float* summ  = rpart + (size_t)BB * 4 * 64;          // B*N*8 row summaries

    const float* mb     = (const float*)d_in[31];
    const float* r_bias = (const float*)d_in[29];
    const float* w_bias = (const float*)d_in[30];

    k_params<<<BB, 256, 0, stream>>>(in, params);
    k_summ<<<BB * 8, 256, 0, stream>>>(mb, params, summ);
    k_combine2<<<BB, 512, 0, stream>>>(summ, w_bias, r_bias, params, bufW, bufR);
    k_read_partial<<<BB * 4, 256, 0, stream>>>(mb, params, bufW, bufR, rpart);
    k_out<<<BB, 64, 0, stream>>>(rpart, (const float*)d_in[3], (const float*)d_in[4],
                                 (float*)d_out);
}

// Round 7
// 62.968 us; speedup vs baseline: 2.2757x; 1.2277x over previous
//
#include <hip/hip_runtime.h>
#include <hip/hip_bf16.h>
#include <math.h>

#define BB 256
#define NN 2048
#define MM 64
#define INF_ 128
#define HH 100
#define EPSF 1e-8f

struct Ptrs { const float* p[32]; };

__device__ __forceinline__ float softplusf(float x) {
    return fmaxf(x, 0.0f) + log1pf(__expf(-fabsf(x)));
}
__device__ __forceinline__ float sigmoidf(float x) {
    return 1.0f / (1.0f + __expf(-x));
}
// fast positive-base pow; |rel err| ~1e-6, far under the 1.36e-2 threshold
__device__ __forceinline__ float fpowf(float x, float g) {
    return __expf(g * __logf(x));
}

// block-wide (16 waves) reduction of two values
__device__ __forceinline__ void bredN(float& a, float& b, bool ismax, float* red)
{
    #pragma unroll
    for (int m = 32; m; m >>= 1) {
        float ta = __shfl_xor(a, m), tb = __shfl_xor(b, m);
        if (ismax) { a = fmaxf(a, ta); b = fmaxf(b, tb); }
        else       { a += ta; b += tb; }
    }
    const int wid = threadIdx.x >> 6;
    if ((threadIdx.x & 63) == 0) { red[wid] = a; red[16 + wid] = b; }
    __syncthreads();
    float ra = red[0], rb = red[16];
    #pragma unroll
    for (int w = 1; w < 16; ++w) {
        if (ismax) { ra = fmaxf(ra, red[w]); rb = fmaxf(rb, red[16 + w]); }
        else       { ra += red[w]; rb += red[16 + w]; }
    }
    __syncthreads();
    a = ra; b = rb;
}

// ---------------------------------------------------------------------------
// One block per batch row b (1024 thr). Phases:
//  A) controller h + all head params (LDS)
//  B) one pass over mb rows -> 8 summaries/row into LDS (64 KB)
//  C) write-head softmax pipeline -> watt (LDS); read-head (algebraic logits
//     from summaries + watt) -> ratt (LDS)
//  D) second pass over mb (L3-hot) -> weighted sums -> r -> out GEMV
// psc: [0]=coef_w [1]=coef_r [2]=gamma_w [3]=gamma_r [4]=g_w [5]=g_r
//      [6..8]=s_w [9..11]=s_r [12]=kra [13]=saa [15]=sp(beta_w) [16]=sp(beta_r)
// ---------------------------------------------------------------------------
__global__ void __launch_bounds__(1024) k_fused(Ptrs in,
                                                const float* __restrict__ mb,
                                                float* __restrict__ out)
{
    __shared__ float xs[INF_];
    __shared__ float hs[HH];
    __shared__ float pk_w[MM], pk_r[MM], pe[MM], pa[MM];
    __shared__ float psc[20];
    __shared__ __align__(16) float summ_l[NN * 8];   // 64 KB
    __shared__ float wcs[NN];
    __shared__ float ats[NN];
    __shared__ float watt[NN];
    __shared__ float ratt[NN];
    __shared__ float red[32];
    __shared__ float wp1[16 * 64];
    __shared__ float wp2[16 * 64];
    __shared__ float rv[64];

    const int b = blockIdx.x, tid = threadIdx.x;
    const int lane = tid & 63, wv = tid >> 6;       // 16 waves
    const int grp = tid >> 3, l8 = tid & 7;         // 128 groups of 8

    // ---------------- Phase A: params ----------------
    if (tid < INF_) xs[tid] = in.p[0][b * INF_ + tid];
    __syncthreads();

    if (tid < HH) {
        const float* Wc = in.p[1];
        float acc = in.p[2][tid];
        #pragma unroll 8
        for (int i = 0; i < INF_; ++i)
            acc = fmaf(xs[i], Wc[i * HH + tid], acc);
        hs[tid] = acc;
    }
    __syncthreads();

    if (wv < 4) {
        // 64-wide heads: wave 0 -> k_w, 1 -> k_r, 2 -> e, 3 -> a
        const int m = lane;
        const float* W; const float* bi;
        if      (wv == 0) { W = in.p[23]; bi = in.p[24]; }
        else if (wv == 1) { W = in.p[13]; bi = in.p[14]; }
        else if (wv == 2) { W = in.p[25]; bi = in.p[26]; }
        else              { W = in.p[27]; bi = in.p[28]; }
        float acc = bi[m];
        #pragma unroll 10
        for (int j = 0; j < HH; ++j)
            acc = fmaf(hs[j], W[j * 64 + m], acc);
        if      (wv == 0) pk_w[m] = acc;
        else if (wv == 1) pk_r[m] = acc;
        else if (wv == 2) pe[m]   = sigmoidf(acc);
        else              pa[m]   = acc;
    } else {
        // 12 scalar heads, one per wave
        const int s = wv - 4;
        const float* W; float bia; int strd = 1, c = 0;
        if      (s == 0) { W = in.p[15]; bia = in.p[16][0]; }
        else if (s == 1) { W = in.p[17]; bia = in.p[18][0]; }
        else if (s == 2) { W = in.p[19]; bia = in.p[20][0]; }
        else if (s == 3) { W = in.p[5];  bia = in.p[6][0]; }
        else if (s == 4) { W = in.p[7];  bia = in.p[8][0]; }
        else if (s == 5) { W = in.p[9];  bia = in.p[10][0]; }
        else if (s < 9)  { W = in.p[21]; c = s - 6; bia = in.p[22][c]; strd = 3; }
        else             { W = in.p[11]; c = s - 9; bia = in.p[12][c]; strd = 3; }
        float v = 0.f;
        if (lane < HH)      v = hs[lane] * W[lane * strd + c];
        if (lane < HH - 64) v = fmaf(hs[lane + 64], W[(lane + 64) * strd + c], v);
        #pragma unroll
        for (int m2 = 32; m2; m2 >>= 1) v += __shfl_xor(v, m2);
        if (lane == 0) {
            float r = v + bia;
            if      (s == 0) psc[15] = softplusf(r);
            else if (s == 1) psc[2]  = 1.0f + softplusf(r);
            else if (s == 2) psc[4]  = sigmoidf(r);
            else if (s == 3) psc[16] = softplusf(r);
            else if (s == 4) psc[3]  = 1.0f + softplusf(r);
            else if (s == 5) psc[5]  = sigmoidf(r);
            else if (s < 9)  psc[6 + c] = r;
            else             psc[9 + c] = r;
        }
    }
    __syncthreads();

    if (wv == 0) {
        float v = pk_w[lane] * pk_w[lane];
        #pragma unroll
        for (int m2 = 32; m2; m2 >>= 1) v += __shfl_xor(v, m2);
        if (lane == 0) psc[0] = psc[15] / fmaxf(sqrtf(v), EPSF);
    }
    if (wv == 1) {
        float v = pk_r[lane] * pk_r[lane];
        #pragma unroll
        for (int m2 = 32; m2; m2 >>= 1) v += __shfl_xor(v, m2);
        if (lane == 0) psc[1] = psc[16] / fmaxf(sqrtf(v), EPSF);
    }
    if (wv == 2) {
        float v = pk_r[lane] * pa[lane];
        #pragma unroll
        for (int m2 = 32; m2; m2 >>= 1) v += __shfl_xor(v, m2);
        if (lane == 0) psc[12] = v;
    }
    if (wv == 3) {
        float v = pa[lane] * pa[lane];
        #pragma unroll
        for (int m2 = 32; m2; m2 >>= 1) v += __shfl_xor(v, m2);
        if (lane == 0) psc[13] = v;
    }
    __syncthreads();

    // ---------------- Phase B: summaries pass over mb ----------------
    {
        float kw[8], kr[8], ev[8], av[8];
        #pragma unroll
        for (int j = 0; j < 8; ++j) {
            kw[j] = pk_w[l8 * 8 + j];
            kr[j] = pk_r[l8 * 8 + j];
            ev[j] = pe[l8 * 8 + j];
            av[j] = pa[l8 * 8 + j];
        }
        const float4* base = reinterpret_cast<const float4*>(mb + (size_t)b * NN * MM);

        #pragma unroll 4
        for (int it = 0; it < 16; ++it) {
            const int n = it * 128 + grp;
            float4 v0 = base[n * 16 + 2 * l8];
            float4 v1 = base[n * 16 + 2 * l8 + 1];
            float f[8] = {v0.x, v0.y, v0.z, v0.w, v1.x, v1.y, v1.z, v1.w};

            float acc[8];
            #pragma unroll
            for (int j = 0; j < 8; ++j) acc[j] = 0.f;
            #pragma unroll
            for (int j = 0; j < 8; ++j) {
                const float m = f[j], m2 = m * m;
                const float x = ev[j] * m, y = ev[j] * m2;
                acc[0] = fmaf(kw[j], m,  acc[0]);   // lw
                acc[1] = fmaf(kr[j], m,  acc[1]);   // d1
                acc[2] = fmaf(kr[j], x,  acc[2]);   // d2
                acc[3] += m2;                       // s0
                acc[4] += y;                        // s1
                acc[5] = fmaf(ev[j], y,  acc[5]);   // s2
                acc[6] = fmaf(av[j], m,  acc[6]);   // s3
                acc[7] = fmaf(av[j], x,  acc[7]);   // s4
            }

            // transposing butterfly: lane l8 ends with acc[l8]
            float k1[4];
            #pragma unroll
            for (int k = 0; k < 4; ++k) {
                float snd = (l8 & 1) ? acc[2 * k] : acc[2 * k + 1];
                float rcv = __shfl_xor(snd, 1);
                k1[k] = ((l8 & 1) ? acc[2 * k + 1] : acc[2 * k]) + rcv;
            }
            float k2[2];
            #pragma unroll
            for (int k = 0; k < 2; ++k) {
                float snd = (l8 & 2) ? k1[2 * k] : k1[2 * k + 1];
                float rcv = __shfl_xor(snd, 2);
                k2[k] = ((l8 & 2) ? k1[2 * k + 1] : k1[2 * k]) + rcv;
            }
            float snd = (l8 & 4) ? k2[0] : k2[1];
            float rcv = __shfl_xor(snd, 4);
            summ_l[n * 8 + l8] = ((l8 & 4) ? k2[1] : k2[0]) + rcv;
        }
    }
    __syncthreads();

    const float kra = psc[12], saa = psc[13];

    // ---------------- Phase C: head 0 (write) ----------------
    {
        const float g = psc[4], gamma = psc[2];
        const float s0c = psc[6], s1c = psc[7], s2c = psc[8];
        const float coef = psc[0];

        float mL = -1e30f, mB = -1e30f;
        #pragma unroll
        for (int k = 0; k < 2; ++k) {
            int i = tid + k * 1024;
            const float4 q0 = reinterpret_cast<const float4*>(summ_l + i * 8)[0];
            float lg = coef * q0.x / fmaxf(sqrtf(q0.w), EPSF);
            wcs[i] = lg; mL = fmaxf(mL, lg);
            float bb = in.p[30][(size_t)b * NN + i]; ats[i] = bb; mB = fmaxf(mB, bb);
        }
        __syncthreads();
        bredN(mL, mB, true, red);

        float sL = 0.f, sB = 0.f;
        #pragma unroll
        for (int k = 0; k < 2; ++k) {
            int i = tid + k * 1024;
            float ew = __expf(wcs[i] - mL);
            float eb = __expf(ats[i] - mB);
            wcs[i] = ew; ats[i] = eb;
            sL += ew; sB += eb;
        }
        bredN(sL, sB, false, red);
        const float iL = 1.0f / sL, iB = 1.0f / sB;

        #pragma unroll
        for (int k = 0; k < 2; ++k) {
            int i = tid + k * 1024;
            ats[i] = g * wcs[i] * iL + (1.0f - g) * ats[i] * iB;
        }
        __syncthreads();

        float pv[2]; float ps = 0.f;
        #pragma unroll
        for (int k = 0; k < 2; ++k) {
            int i = tid + k * 1024;
            float tw = s0c * ats[(i + NN - 1) & (NN - 1)]
                     + s1c * ats[i]
                     + s2c * ats[(i + 1) & (NN - 1)];
            float p = fpowf(tw, gamma);
            pv[k] = p; ps += p;
        }
        float dmy = 0.f;
        bredN(ps, dmy, false, red);
        const float inv = 1.0f / (EPSF + ps);
        #pragma unroll
        for (int k = 0; k < 2; ++k) {
            int i = tid + k * 1024;
            watt[i] = pv[k] * inv;
        }
        __syncthreads();
    }

    // ---------------- Phase C: head 1 (read) ----------------
    {
        const float g = psc[5], gamma = psc[3];
        const float s0c = psc[9], s1c = psc[10], s2c = psc[11];
        const float coef = psc[1];

        float mL = -1e30f, mB = -1e30f;
        #pragma unroll
        for (int k = 0; k < 2; ++k) {
            int i = tid + k * 1024;
            const float4* sp = reinterpret_cast<const float4*>(summ_l + i * 8);
            const float4 q0 = sp[0];
            const float4 q1 = sp[1];
            const float w = watt[i];
            const float dot = q0.y + w * (kra - q0.z);
            float nrm2 = q0.w + 2.f * w * (q1.z - q1.x)
                       + w * w * (q1.y + saa - 2.f * q1.w);
            nrm2 = fmaxf(nrm2, 0.f);
            float lg = coef * dot / fmaxf(sqrtf(nrm2), EPSF);
            wcs[i] = lg; mL = fmaxf(mL, lg);
            float bb = in.p[29][(size_t)b * NN + i]; ats[i] = bb; mB = fmaxf(mB, bb);
        }
        __syncthreads();
        bredN(mL, mB, true, red);

        float sL = 0.f, sB = 0.f;
        #pragma unroll
        for (int k = 0; k < 2; ++k) {
            int i = tid + k * 1024;
            float ew = __expf(wcs[i] - mL);
            float eb = __expf(ats[i] - mB);
            wcs[i] = ew; ats[i] = eb;
            sL += ew; sB += eb;
        }
        bredN(sL, sB, false, red);
        const float iL = 1.0f / sL, iB = 1.0f / sB;

        #pragma unroll
        for (int k = 0; k < 2; ++k) {
            int i = tid + k * 1024;
            ats[i] = g * wcs[i] * iL + (1.0f - g) * ats[i] * iB;
        }
        __syncthreads();

        float pv[2]; float ps = 0.f;
        #pragma unroll
        for (int k = 0; k < 2; ++k) {
            int i = tid + k * 1024;
            float tw = s0c * ats[(i + NN - 1) & (NN - 1)]
                     + s1c * ats[i]
                     + s2c * ats[(i + 1) & (NN - 1)];
            float p = fpowf(tw, gamma);
            pv[k] = p; ps += p;
        }
        float dmy = 0.f;
        bredN(ps, dmy, false, red);
        const float inv = 1.0f / (EPSF + ps);
        #pragma unroll
        for (int k = 0; k < 2; ++k) {
            int i = tid + k * 1024;
            ratt[i] = pv[k] * inv;
        }
        __syncthreads();
    }

    // ---------------- Phase D: weighted read + output ----------------
    // r = S1 - e.*S2 + t*a,  S1 = sum ra*mb, S2 = sum (ra*w)*mb, t = sum ra*w
    float tval = ratt[tid] * watt[tid] + ratt[tid + 1024] * watt[tid + 1024];
    {
        float dmy = 0.f;
        bredN(tval, dmy, false, red);
    }

    {
        float a1[8], a2[8];
        #pragma unroll
        for (int j = 0; j < 8; ++j) { a1[j] = 0.f; a2[j] = 0.f; }
        const float4* base = reinterpret_cast<const float4*>(mb + (size_t)b * NN * MM);

        #pragma unroll 4
        for (int it = 0; it < 16; ++it) {
            const int n = it * 128 + grp;
            const float c1 = ratt[n];
            const float c2 = c1 * watt[n];
            float4 v0 = base[n * 16 + 2 * l8];
            float4 v1 = base[n * 16 + 2 * l8 + 1];
            float f[8] = {v0.x, v0.y, v0.z, v0.w, v1.x, v1.y, v1.z, v1.w};
            #pragma unroll
            for (int j = 0; j < 8; ++j) {
                a1[j] = fmaf(c1, f[j], a1[j]);
                a2[j] = fmaf(c2, f[j], a2[j]);
            }
        }
        // reduce across the 8 groups within each wave
        #pragma unroll
        for (int j = 0; j < 8; ++j) {
            #pragma unroll
            for (int mask = 8; mask < 64; mask <<= 1) {
                a1[j] += __shfl_xor(a1[j], mask);
                a2[j] += __shfl_xor(a2[j], mask);
            }
        }
        if (lane < 8) {
            #pragma unroll
            for (int j = 0; j < 8; ++j) {
                wp1[wv * 64 + lane * 8 + j] = a1[j];
                wp2[wv * 64 + lane * 8 + j] = a2[j];
            }
        }
    }
    __syncthreads();

    if (tid < 64) {
        float S1 = 0.f, S2 = 0.f;
        #pragma unroll
        for (int w8 = 0; w8 < 16; ++w8) {
            S1 += wp1[w8 * 64 + tid];
            S2 += wp2[w8 * 64 + tid];
        }
        rv[tid] = S1 - pe[tid] * S2 + tval * pa[tid];
    }
    __syncthreads();

    if (tid < 64) {
        const float* Wo = in.p[3];
        float o = in.p[4][tid];
        #pragma unroll 4
        for (int m = 0; m < 64; ++m) o = fmaf(rv[m], Wo[m * 64 + tid], o);
        out[(size_t)b * 64 + tid] = sigmoidf(o);
    }
}

// ---------------------------------------------------------------------------
extern "C" void kernel_launch(void* const* d_in, const int* in_sizes, int n_in,
                              void* d_out, int out_size, void* d_ws, size_t ws_size,
                              hipStream_t stream)
{
    Ptrs in;
    for (int i = 0; i < 32; ++i) in.p[i] = (const float*)d_in[i];
    const float* mb = (const float*)d_in[31];

    k_fused<<<BB, 1024, 0, stream>>>(in, mb, (float*)d_out);
}